// Round 4
// baseline (7953.128 us; speedup 1.0000x reference)
//
#include <hip/hip_runtime.h>
#include <hip/hip_bf16.h>
#include <math.h>

typedef __hip_bfloat16 bf16;

__device__ __forceinline__ float u2f(unsigned short u){ union { unsigned int i; float f; } z; z.i = ((unsigned int)u) << 16; return z.f; }
__device__ __forceinline__ unsigned short f2u(float f){ bf16 h = __float2bfloat16(f); return *(unsigned short*)&h; }

// ---- bev_feature chunk [8b, D=512, P=256] fp32 -> tokens [8b*256, 512] fp32 (transpose) ----
__global__ void k_bev_tok(const float* __restrict__ bev, float* __restrict__ out, int b0){
  __shared__ float tile[32][33];
  int bl = blockIdx.z;            // local b within chunk (0..7)
  int b  = b0 + bl;
  int d0 = blockIdx.x * 32;
  int p0 = blockIdx.y * 32;
  int tx = threadIdx.x, ty = threadIdx.y; // 32 x 8
  #pragma unroll
  for (int i = 0; i < 4; i++){
    int d = d0 + ty + i*8;
    tile[ty + i*8][tx] = bev[((size_t)b*512 + d)*256 + p0 + tx];
  }
  __syncthreads();
  #pragma unroll
  for (int i = 0; i < 4; i++){
    int p = p0 + ty + i*8;
    out[((size_t)bl*256 + p)*512 + d0 + tx] = tile[tx][ty + i*8];
  }
}

// ---- GEMM: C[r,n] = sum_k A[r,k]*W[n,k] + bias[n] (all fp32); rows%64==0, Nc%64==0, Kd%32==0 ----
__global__ __launch_bounds__(256) void k_gemm(const float* __restrict__ A, const float* __restrict__ W,
                                              const float* __restrict__ bias, float* __restrict__ C,
                                              int Kd, int Nc)
{
  __shared__ float As[32][68];
  __shared__ float Ws[32][68];
  int rb = blockIdx.x * 64, nb = blockIdx.y * 64;
  int tid = threadIdx.x;
  int tx = tid & 15, ty = tid >> 4;
  int r = tid >> 2;
  int c0 = (tid & 3) * 8;
  const float* Aptr = A + (size_t)(rb + r) * Kd + c0;
  const float* Wptr = W + (size_t)(nb + r) * Kd + c0;
  float acc[4][4] = {};
  for (int k0 = 0; k0 < Kd; k0 += 32){
    float4 a0 = *(const float4*)(Aptr + k0);
    float4 a1 = *(const float4*)(Aptr + k0 + 4);
    float4 w0 = *(const float4*)(Wptr + k0);
    float4 w1 = *(const float4*)(Wptr + k0 + 4);
    As[c0+0][r] = a0.x; As[c0+1][r] = a0.y; As[c0+2][r] = a0.z; As[c0+3][r] = a0.w;
    As[c0+4][r] = a1.x; As[c0+5][r] = a1.y; As[c0+6][r] = a1.z; As[c0+7][r] = a1.w;
    Ws[c0+0][r] = w0.x; Ws[c0+1][r] = w0.y; Ws[c0+2][r] = w0.z; Ws[c0+3][r] = w0.w;
    Ws[c0+4][r] = w1.x; Ws[c0+5][r] = w1.y; Ws[c0+6][r] = w1.z; Ws[c0+7][r] = w1.w;
    __syncthreads();
    #pragma unroll
    for (int kk = 0; kk < 32; kk++){
      float4 a4 = *(const float4*)&As[kk][ty*4];
      float4 w4 = *(const float4*)&Ws[kk][tx*4];
      float ar[4] = {a4.x, a4.y, a4.z, a4.w};
      float wr[4] = {w4.x, w4.y, w4.z, w4.w};
      #pragma unroll
      for (int i = 0; i < 4; i++)
        #pragma unroll
        for (int j = 0; j < 4; j++)
          acc[i][j] += ar[i]*wr[j];
    }
    __syncthreads();
  }
  #pragma unroll
  for (int i = 0; i < 4; i++){
    size_t rr = (size_t)(rb + ty*4 + i);
    #pragma unroll
    for (int j = 0; j < 4; j++){
      int n = nb + tx*4 + j;
      C[rr*Nc + n] = acc[i][j] + bias[n];
    }
  }
}

// ---- row LayerNorm (D=512) fp32, optional residual, optional relu ----
__global__ __launch_bounds__(256) void k_ln(const float* __restrict__ X, const float* __restrict__ R,
                                            const float* __restrict__ g, const float* __restrict__ bt,
                                            float* __restrict__ out, int relu)
{
  __shared__ float red[4];
  int row = blockIdx.x, t = threadIdx.x;
  size_t base = (size_t)row * 512;
  float x0 = X[base + t], x1 = X[base + t + 256];
  if (R){ x0 += R[base + t]; x1 += R[base + t + 256]; }
  float v = x0 + x1;
  #pragma unroll
  for (int o = 32; o > 0; o >>= 1) v += __shfl_xor(v, o);
  if ((t & 63) == 0) red[t >> 6] = v;
  __syncthreads();
  float mean = (red[0]+red[1]+red[2]+red[3]) * (1.0f/512.0f);
  float d0 = x0 - mean, d1 = x1 - mean;
  v = d0*d0 + d1*d1;
  #pragma unroll
  for (int o = 32; o > 0; o >>= 1) v += __shfl_xor(v, o);
  __syncthreads();
  if ((t & 63) == 0) red[t >> 6] = v;
  __syncthreads();
  float var = (red[0]+red[1]+red[2]+red[3]) * (1.0f/512.0f);
  float is = 1.0f / sqrtf(var + 1e-5f);
  float y0 = d0*is*g[t] + bt[t];
  float y1 = d1*is*g[t+256] + bt[t+256];
  if (relu){ y0 = fmaxf(y0, 0.0f); y1 = fmaxf(y1, 0.0f); }
  out[base + t] = y0;
  out[base + t + 256] = y1;
}

// ---- top-K agents + invalid mask ----
__global__ void k_topk(const float* __restrict__ labels, const float* __restrict__ states,
                       int* __restrict__ idxo, int* __restrict__ invo)
{
  __shared__ float dist[32];
  __shared__ int valid[32];
  int b = blockIdx.x, t = threadIdx.x;
  if (t < 32){
    float lab = labels[b*32 + t];
    float sg = 1.0f / (1.0f + expf(-lab));
    int va = sg > 0.05f;
    float x = states[((size_t)b*32 + t)*8 + 0];
    float y = states[((size_t)b*32 + t)*8 + 1];
    float d = sqrtf(__fadd_rn(__fmul_rn(x,x), __fmul_rn(y,y)));
    dist[t] = va ? d : INFINITY;
    valid[t] = va;
  }
  __syncthreads();
  if (t == 0){
    unsigned used = 0;
    int inv8[8]; int allinv = 1;
    for (int kk = 0; kk < 8; kk++){
      float best = INFINITY; int bi = -1;
      for (int i = 0; i < 32; i++){
        if (used & (1u << i)) continue;
        if (bi < 0 || dist[i] < best){ best = dist[i]; bi = i; }
      }
      used |= 1u << bi;
      idxo[b*8 + kk] = bi;
      inv8[kk] = !valid[bi];
      allinv &= inv8[kk];
    }
    for (int kk = 0; kk < 8; kk++) invo[b*8 + kk] = allinv ? 0 : inv8[kk];
  }
}

// ---- gather selected agents -> [512, 512] fp32 ----
__global__ void k_gather(const float* __restrict__ aq, const int* __restrict__ idx, float* __restrict__ out)
{
  int rk = blockIdx.x; int b = rk >> 3;
  int src = idx[rk] & 31;
  int t = threadIdx.x;
  size_t sbase = ((size_t)(b*32 + src))*512;
  out[(size_t)rk*512 + t]       = aq[sbase + t];
  out[(size_t)rk*512 + t + 256] = aq[sbase + t + 256];
}

// ---- agent_kv[(b*K+k)*T+t, :] = enc[b*K+k,:] + step_e[t,:] + role_e[1,:] ----
__global__ void k_agentkv(const float* __restrict__ enc, const float* __restrict__ step_e,
                          const float* __restrict__ role_e, float* __restrict__ out)
{
  int row = blockIdx.x;
  int t8 = row & 7; int bk = row >> 3;
  int tx = threadIdx.x;
  #pragma unroll
  for (int j = 0; j < 2; j++){
    int d = tx + j*256;
    out[(size_t)row*512 + d] = (enc[(size_t)bk*512 + d] + step_e[t8*512 + d]) + role_e[512 + d];
  }
}

// ---- sequential codebook NN scan -> tokens [B, T] (identical across modes) ----
__global__ __launch_bounds__(64) void k_cbscan(const float* __restrict__ gt, const float* __restrict__ cb,
                                               int* __restrict__ toks)
{
  __shared__ float cbx[512], cby[512];
  int b = blockIdx.x;
  int l = threadIdx.x;
  #pragma unroll
  for (int i = 0; i < 8; i++){
    int v = l + i*64;
    cbx[v] = cb[v*2 + 0];
    cby[v] = cb[v*2 + 1];
  }
  __syncthreads();
  float ax = 0.0f, ay = 0.0f;
  for (int t = 0; t < 8; t++){
    float px = gt[(b*8 + t)*3 + 0];
    float py = gt[(b*8 + t)*3 + 1];
    float bestv = INFINITY; int besti = 0;   // argmin(all-NaN) = 0, and always in-bounds
    #pragma unroll
    for (int i = 0; i < 8; i++){
      int v = l*8 + i;
      float dx = __fsub_rn(__fadd_rn(ax, cbx[v]), px);
      float dy = __fsub_rn(__fadd_rn(ay, cby[v]), py);
      float d = __fadd_rn(__fmul_rn(dx,dx), __fmul_rn(dy,dy));
      if (d < bestv || (d == bestv && v < besti)){ bestv = d; besti = v; }
    }
    #pragma unroll
    for (int o = 32; o > 0; o >>= 1){
      float ov = __shfl_xor(bestv, o);
      int oi = __shfl_xor(besti, o);
      if (ov < bestv || (ov == bestv && oi < besti)){ bestv = ov; besti = oi; }
    }
    ax = __fadd_rn(ax, cbx[besti]);
    ay = __fadd_rn(ay, cby[besti]);
    if (l == 0) toks[b*8 + t] = besti;
  }
}

// ---- teacher-forced embedding -> egoq [10240, 512] fp32 ----
__global__ void k_embed(const int* __restrict__ toks, const float* __restrict__ ebase,
                        const float* __restrict__ tok_emb, const float* __restrict__ step_e,
                        const float* __restrict__ mode_e, const float* __restrict__ role_e,
                        const float* __restrict__ bos_e, float* __restrict__ out)
{
  int row = blockIdx.x;            // (b*M+m)*T + t
  int t = row & 7; int bm = row >> 3; int m = bm % 20; int b = bm / 20;
  int tok = (t == 0) ? 0 : (toks[b*8 + t - 1] & 511);
  int tx = threadIdx.x;
  #pragma unroll
  for (int j = 0; j < 2; j++){
    int d = tx + j*256;
    float base = (t == 0) ? (bos_e[d] + ebase[(size_t)b*512 + d])
                          : tok_emb[(size_t)tok*512 + d];
    out[(size_t)row*512 + d] = ((base + step_e[t*512 + d]) + role_e[d]) + mode_e[m*512 + d];
  }
}

// ---- temporal causal attention over chunk of 1280 rows (QKV [1280,1536] fp32) ----
__global__ __launch_bounds__(64) void k_tattn(const float* __restrict__ QKV, float* __restrict__ O)
{
  __shared__ float q[8][65], k[8][65], v[8][65], w[8][9];
  int h = blockIdx.x & 7; int bm = blockIdx.x >> 3;  // bm < 160
  int l = threadIdx.x;
  for (int t = 0; t < 8; t++){
    size_t base = ((size_t)(bm*8 + t))*1536 + h*64 + l;
    q[t][l] = QKV[base];
    k[t][l] = QKV[base + 512];
    v[t][l] = QKV[base + 1024];
  }
  __syncthreads();
  int tq = l >> 3, tk = l & 7;
  float s = -INFINITY;
  if (tk <= tq){
    float acc = 0.0f;
    #pragma unroll
    for (int e = 0; e < 64; e++) acc += q[tq][e]*k[tk][e];
    s = acc * 0.125f;
  }
  float mx = s;
  #pragma unroll
  for (int o = 1; o < 8; o <<= 1) mx = fmaxf(mx, __shfl_xor(mx, o));
  float ex = (tk <= tq) ? expf(s - mx) : 0.0f;
  float sm = ex;
  #pragma unroll
  for (int o = 1; o < 8; o <<= 1) sm += __shfl_xor(sm, o);
  w[tq][tk] = ex / sm;
  __syncthreads();
  #pragma unroll
  for (int t2 = 0; t2 < 8; t2++){
    float acc = 0.0f;
    #pragma unroll
    for (int tk2 = 0; tk2 < 8; tk2++) acc += w[t2][tk2]*v[tk2][l];
    O[((size_t)(bm*8 + t2))*512 + h*64 + l] = acc;
  }
}

// ---- ego-to-agent cross-attention: Q/O chunk-local [1280,512], Ka/Va global [4096,512] ----
__global__ __launch_bounds__(64) void k_eattn(const float* __restrict__ Q, const float* __restrict__ Ka,
                                              const float* __restrict__ Va, const int* __restrict__ inv,
                                              float* __restrict__ O, int row0)
{
  int blk = blockIdx.x;       // local row
  int h = blockIdx.y;
  int grow = row0 + blk;
  int t = grow & 7;
  int b = grow / 160;
  int l = threadIdx.x;
  size_t qoff = (size_t)blk*512 + h*64 + l;
  float q = Q[qoff];
  float s[8];
  #pragma unroll
  for (int k = 0; k < 8; k++){
    float p = q * Ka[((size_t)((b*8 + k)*8 + t))*512 + h*64 + l];
    #pragma unroll
    for (int o = 32; o > 0; o >>= 1) p += __shfl_xor(p, o);
    s[k] = p * 0.125f;
  }
  float mx = -INFINITY;
  #pragma unroll
  for (int k = 0; k < 8; k++){
    if (inv[b*8 + k]) s[k] = -INFINITY;
    mx = fmaxf(mx, s[k]);
  }
  float sum = 0.0f, w[8];
  #pragma unroll
  for (int k = 0; k < 8; k++){ w[k] = expf(s[k] - mx); sum += w[k]; }
  float rs = 1.0f / sum;
  float acc = 0.0f;
  #pragma unroll
  for (int k = 0; k < 8; k++) acc += (w[k]*rs) * Va[((size_t)((b*8 + k)*8 + t))*512 + h*64 + l];
  O[qoff] = acc;
}

// ---- BEV cross-attention: Q/O [1280,512], K/V [2048,512] fp32; K staged bf16 in LDS; grid (8,8,4) ----
__global__ __launch_bounds__(256) void k_vattn(const float* __restrict__ Q, const float* __restrict__ Kb,
                                               const float* __restrict__ Vb, float* __restrict__ O)
{
  __shared__ unsigned short Ks[256][66];
  __shared__ float qs[4][64];
  __shared__ float wgt[4][256];
  __shared__ float part[4][4][64];
  __shared__ float red[4][4];
  int bl = blockIdx.x;          // local b (0..7)
  int h = blockIdx.y, qc = blockIdx.z;
  int tid = threadIdx.x;
  for (int i = 0; i < 64; i++){
    int idx = i*256 + tid;
    int p = idx >> 6, e = idx & 63;
    Ks[p][e] = f2u(Kb[((size_t)(bl*256 + p))*512 + h*64 + e]);
  }
  __syncthreads();
  int g = tid >> 6, e = tid & 63;
  for (int q0 = qc*40; q0 < qc*40 + 40; q0 += 4){
    {
      int q = tid >> 6; int ee = tid & 63;
      qs[q][ee] = Q[((size_t)(bl*160 + q0 + q))*512 + h*64 + ee];
    }
    __syncthreads();
    float s[4] = {0,0,0,0};
    #pragma unroll 8
    for (int e2 = 0; e2 < 64; e2 += 2){
      float k0 = u2f(Ks[tid][e2]);
      float k1 = u2f(Ks[tid][e2+1]);
      #pragma unroll
      for (int q = 0; q < 4; q++) s[q] += qs[q][e2]*k0 + qs[q][e2+1]*k1;
    }
    #pragma unroll
    for (int q = 0; q < 4; q++){
      float sv = s[q]*0.125f;
      s[q] = sv;
      float mx = sv;
      #pragma unroll
      for (int o = 32; o > 0; o >>= 1) mx = fmaxf(mx, __shfl_xor(mx, o));
      if ((tid & 63) == 0) red[q][tid >> 6] = mx;
    }
    __syncthreads();
    float ex[4];
    #pragma unroll
    for (int q = 0; q < 4; q++){
      float mx = fmaxf(fmaxf(red[q][0],red[q][1]), fmaxf(red[q][2],red[q][3]));
      ex[q] = expf(s[q] - mx);
    }
    __syncthreads();
    #pragma unroll
    for (int q = 0; q < 4; q++){
      float sm = ex[q];
      #pragma unroll
      for (int o = 32; o > 0; o >>= 1) sm += __shfl_xor(sm, o);
      if ((tid & 63) == 0) red[q][tid >> 6] = sm;
    }
    __syncthreads();
    #pragma unroll
    for (int q = 0; q < 4; q++){
      float sm = red[q][0]+red[q][1]+red[q][2]+red[q][3];
      wgt[q][tid] = ex[q] / sm;
    }
    __syncthreads();
    float acc[4] = {0,0,0,0};
    for (int j = 0; j < 64; j++){
      int p = g*64 + j;
      float v = Vb[((size_t)(bl*256 + p))*512 + h*64 + e];
      #pragma unroll
      for (int q = 0; q < 4; q++) acc[q] += wgt[q][p]*v;
    }
    #pragma unroll
    for (int q = 0; q < 4; q++) part[g][q][e] = acc[q];
    __syncthreads();
    {
      int q = tid >> 6; int ee = tid & 63;
      float o = part[0][q][ee]+part[1][q][ee]+part[2][q][ee]+part[3][q][ee];
      O[((size_t)(bl*160 + q0 + q))*512 + h*64 + ee] = o;
    }
    __syncthreads();
  }
}

// ---- exact GELU (erf), in place ----
__global__ void k_gelu(float* __restrict__ x, size_t n){
  size_t i = (size_t)blockIdx.x*256 + threadIdx.x;
  if (i < n){
    float v = x[i];
    x[i] = 0.5f*v*(1.0f + erff(v*0.70710678118654752f));
  }
}

// ---- copy 1280 rows of 512 ----
__global__ void k_copyrows(const float* __restrict__ src, float* __restrict__ dst){
  int r = blockIdx.x, t = threadIdx.x;
  dst[(size_t)r*512 + t]       = src[(size_t)r*512 + t];
  dst[(size_t)r*512 + t + 256] = src[(size_t)r*512 + t + 256];
}

extern "C" void kernel_launch(void* const* d_in, const int* in_sizes, int n_in,
                              void* d_out, int out_size, void* d_ws, size_t ws_size,
                              hipStream_t stream)
{
  (void)in_sizes; (void)n_in; (void)out_size;
  const float* ego_query    = (const float*)d_in[0];
  const float* agents_query = (const float*)d_in[1];
  const float* bev_feature  = (const float*)d_in[2];
  const float* agent_states = (const float*)d_in[3];
  const float* agent_labels = (const float*)d_in[4];
  const float* gt_traj      = (const float*)d_in[5];
  const float* codebook     = (const float*)d_in[6];
  const float* ego_ctx_w    = (const float*)d_in[7];
  const float* ego_ctx_b    = (const float*)d_in[8];
  const float* ego_ctx_g    = (const float*)d_in[9];
  const float* ego_ctx_beta = (const float*)d_in[10];
  const float* bevproj_w    = (const float*)d_in[11];
  const float* bevproj_b    = (const float*)d_in[12];
  const float* bevproj_g    = (const float*)d_in[13];
  const float* bevproj_beta = (const float*)d_in[14];
  const float* agent_w      = (const float*)d_in[15];
  const float* agent_b      = (const float*)d_in[16];
  const float* agent_g      = (const float*)d_in[17];
  const float* agent_beta   = (const float*)d_in[18];
  const float* tok_emb      = (const float*)d_in[19];
  const float* step_e       = (const float*)d_in[20];
  const float* mode_e       = (const float*)d_in[21];
  const float* role_e       = (const float*)d_in[22];
  const float* bos_e        = (const float*)d_in[23];
  const float* t_qkv_w      = (const float*)d_in[24];
  const float* t_qkv_b      = (const float*)d_in[25];
  const float* t_out_w      = (const float*)d_in[26];
  const float* t_out_b      = (const float*)d_in[27];
  const float* t_g          = (const float*)d_in[28];
  const float* t_beta       = (const float*)d_in[29];
  const float* e_qkv_w      = (const float*)d_in[30];
  const float* e_qkv_b      = (const float*)d_in[31];
  const float* e_out_w      = (const float*)d_in[32];
  const float* e_out_b      = (const float*)d_in[33];
  const float* e_g          = (const float*)d_in[34];
  const float* e_beta       = (const float*)d_in[35];
  const float* v_qkv_w      = (const float*)d_in[36];
  const float* v_qkv_b      = (const float*)d_in[37];
  const float* v_out_w      = (const float*)d_in[38];
  const float* v_out_b      = (const float*)d_in[39];
  const float* v_g          = (const float*)d_in[40];
  const float* v_beta       = (const float*)d_in[41];
  const float* ffn_w1       = (const float*)d_in[42];
  const float* ffn_b1       = (const float*)d_in[43];
  const float* ffn_w2       = (const float*)d_in[44];
  const float* ffn_b2       = (const float*)d_in[45];
  const float* ffn_g        = (const float*)d_in[46];
  const float* ffn_beta     = (const float*)d_in[47];
  const float* head_w       = (const float*)d_in[48];
  const float* head_b       = (const float*)d_in[49];

  // ---- workspace layout (fp32 elements) — total 47,847,424 B (~45.6 MB) ----
  float* W0    = (float*)d_ws;
  float* akv   = W0;                 // 2,097,152   [4096,512]
  float* ebase = W0 + 2097152;       //    32,768   [64,512]
  float* A_h   = W0 + 2129920;       // 2,621,440   [1280,2048] / [1280,1536] / [2048,512]
  float* A_k   = W0 + 4751360;       // 2,097,152   [4096,512] (eattn K) / [2048,512] (bev K)
  float* A_v   = W0 + 6848512;       // 2,097,152
  float* A_t   = W0 + 8945664;       // 1,048,576   [2048,512] bev tokens chunk
  float* A_q   = W0 + 9994240;       //   655,360   [1280,512]
  float* A_o   = W0 + 10649600;      //   655,360
  float* A_x   = W0 + 11304960;      //   655,360
  int*  toks   = (int*)(W0 + 11960320);   // 512 ints
  int*  idxb   = toks + 512;
  int*  invb   = idxb + 512;

  const size_t NEEDED = (size_t)11960320*4 + 3*512*4;   // 47,847,424 B
  if (ws_size < NEEDED) return;   // diagnostic: clean absmax failure instead of OOB fault

  float* egoq = (float*)d_out;      // [10240,512] lives in d_out until the head GEMM

  auto gemm = [&](const float* A, const float* W, const float* bias, float* C, int rows, int Kd, int Nc){
    k_gemm<<<dim3(rows/64, Nc/64), 256, 0, stream>>>(A, W, bias, C, Kd, Nc);
  };

  // --- ego base -> ebase ---
  gemm(ego_query, ego_ctx_w, ego_ctx_b, A_h, 64, 512, 512);
  k_ln<<<64, 256, 0, stream>>>(A_h, nullptr, ego_ctx_g, ego_ctx_beta, ebase, 1);

  // --- agents: topk, gather, encode, kv ---
  k_topk<<<64, 64, 0, stream>>>(agent_labels, agent_states, idxb, invb);
  k_gather<<<512, 256, 0, stream>>>(agents_query, idxb, A_h);
  gemm(A_h, agent_w, agent_b, A_k, 512, 512, 512);
  k_ln<<<512, 256, 0, stream>>>(A_k, nullptr, agent_g, agent_beta, A_k, 1);
  k_agentkv<<<4096, 256, 0, stream>>>(A_k, step_e, role_e, akv);

  // --- tokens + embedding ---
  k_cbscan<<<64, 64, 0, stream>>>(gt_traj, codebook, toks);
  k_embed<<<10240, 256, 0, stream>>>(toks, ebase, tok_emb, step_e, mode_e, role_e, bos_e, egoq);

  for (int i = 0; i < 2; i++){
    // ---- temporal self-attention, per 1280-row chunk ----
    for (int c = 0; c < 8; c++){
      int row0 = c*1280;
      gemm(egoq + (size_t)row0*512, t_qkv_w + (size_t)i*786432, t_qkv_b + i*1536, A_h, 1280, 512, 1536);
      k_tattn<<<1280, 64, 0, stream>>>(A_h, A_o);
      gemm(A_o, t_out_w + (size_t)i*262144, t_out_b + i*512, A_x, 1280, 512, 512);
      k_ln<<<1280, 256, 0, stream>>>(A_x, egoq + (size_t)row0*512, t_g + i*512, t_beta + i*512,
                                     egoq + (size_t)row0*512, 0);
    }
    // ---- ego-to-agent cross-attention ----
    {
      const float* eqw = e_qkv_w + (size_t)i*786432;
      const float* eqb = e_qkv_b + i*1536;
      gemm(akv, eqw + 262144, eqb + 512,  A_k, 4096, 512, 512);
      gemm(akv, eqw + 524288, eqb + 1024, A_v, 4096, 512, 512);
      for (int c = 0; c < 8; c++){
        int row0 = c*1280;
        gemm(egoq + (size_t)row0*512, eqw, eqb, A_q, 1280, 512, 512);
        k_eattn<<<dim3(1280, 8), 64, 0, stream>>>(A_q, A_k, A_v, invb, A_o, row0);
        gemm(A_o, e_out_w + (size_t)i*262144, e_out_b + i*512, A_x, 1280, 512, 512);
        k_ln<<<1280, 256, 0, stream>>>(A_x, egoq + (size_t)row0*512, e_g + i*512, e_beta + i*512,
                                       egoq + (size_t)row0*512, 0);
      }
    }
    // ---- BEV cross-attention, per 8-batch chunk (= 1280 ego rows, 2048 bev tokens) ----
    {
      const float* vqw = v_qkv_w + (size_t)i*786432;
      const float* vqb = v_qkv_b + i*1536;
      for (int b0 = 0; b0 < 64; b0 += 8){
        int row0 = b0*160;
        k_bev_tok<<<dim3(16, 8, 8), dim3(32, 8), 0, stream>>>(bev_feature, A_h, b0);
        gemm(A_h, bevproj_w, bevproj_b, A_t, 2048, 512, 512);
        k_ln<<<2048, 256, 0, stream>>>(A_t, nullptr, bevproj_g, bevproj_beta, A_t, 1);
        gemm(A_t, vqw + 262144, vqb + 512,  A_k, 2048, 512, 512);
        gemm(A_t, vqw + 524288, vqb + 1024, A_v, 2048, 512, 512);
        gemm(egoq + (size_t)row0*512, vqw, vqb, A_q, 1280, 512, 512);
        k_vattn<<<dim3(8, 8, 4), 256, 0, stream>>>(A_q, A_k, A_v, A_o);
        gemm(A_o, v_out_w + (size_t)i*262144, v_out_b + i*512, A_x, 1280, 512, 512);
        k_ln<<<1280, 256, 0, stream>>>(A_x, egoq + (size_t)row0*512, v_g + i*512, v_beta + i*512,
                                       egoq + (size_t)row0*512, 0);
      }
    }
    // ---- FFN, per 1280-row chunk ----
    for (int c = 0; c < 8; c++){
      int row0 = c*1280;
      gemm(egoq + (size_t)row0*512, ffn_w1 + (size_t)i*1048576, ffn_b1 + i*2048, A_h, 1280, 512, 2048);
      k_gelu<<<10240, 256, 0, stream>>>(A_h, (size_t)1280*2048);
      gemm(A_h, ffn_w2 + (size_t)i*1048576, ffn_b2 + i*512, A_x, 1280, 2048, 512);
      k_ln<<<1280, 256, 0, stream>>>(A_x, egoq + (size_t)row0*512, ffn_g + i*512, ffn_beta + i*512,
                                     egoq + (size_t)row0*512, 0);
    }
  }

  // --- head: per chunk, copy egoq rows out of d_out then GEMM back into d_out ---
  for (int c = 0; c < 8; c++){
    int row0 = c*1280;
    k_copyrows<<<1280, 256, 0, stream>>>(egoq + (size_t)row0*512, A_q);
    gemm(A_q, head_w, head_b, (float*)d_out + (size_t)row0*512, 1280, 512, 512);
  }
}

// Round 6
// 3612.354 us; speedup vs baseline: 2.2016x; 2.2016x over previous
//
#include <hip/hip_runtime.h>
#include <hip/hip_bf16.h>
#include <math.h>
#include <type_traits>

typedef __hip_bfloat16 bf16;
typedef __attribute__((ext_vector_type(8))) short bf16x8;
typedef __attribute__((ext_vector_type(4))) float f32x4;

__device__ __forceinline__ float b2f(bf16 x){ return __bfloat162float(x); }
__device__ __forceinline__ short f2s(float f){
  bf16 h = __float2bfloat16(f);
  short s; __builtin_memcpy(&s, &h, 2); return s;
}
__device__ __forceinline__ float u2f(unsigned short u){ union { unsigned int i; float f; } z; z.i = ((unsigned int)u) << 16; return z.f; }

// ==================== MFMA GEMM: C[r,n] = act( sum_k A[r,k]*W[n,k] + bias[n] ) ====================
// 128x128 tile, BK=32, 4 waves, 16x16x32 bf16 MFMA, fp32 accum. rows guarded; Kd%32==0; Nc%128==0 or %64 via grid.
template<typename AT, typename CT, int ACT>
__global__ __launch_bounds__(256) void k_gemm_mfma(const AT* __restrict__ A, const float* __restrict__ W,
                                                   const float* __restrict__ bias, CT* __restrict__ C,
                                                   int rows, int Kd, int Nc)
{
  __shared__ short As[128][40];   // 80 B row stride: 16B-aligned, 2-way bank alias (free)
  __shared__ short Bs[128][40];
  int rb = blockIdx.x * 128, nb = blockIdx.y * 128;
  int tid = threadIdx.x;
  int l = tid & 63, w = tid >> 6;
  int wr = (w >> 1) * 64, wc = (w & 1) * 64;
  int lr = l & 15, lk = l >> 4;
  f32x4 acc[4][4];
  #pragma unroll
  for (int i = 0; i < 4; i++)
    #pragma unroll
    for (int j = 0; j < 4; j++)
      acc[i][j] = (f32x4){0.f, 0.f, 0.f, 0.f};
  int sr = tid >> 1;            // staging row 0..127
  int sc = (tid & 1) * 16;      // staging col 0 or 16

  for (int k0 = 0; k0 < Kd; k0 += 32){
    bf16x8 ta0 = {0,0,0,0,0,0,0,0}, ta1 = {0,0,0,0,0,0,0,0};
    bf16x8 tb0, tb1;
    {
      int gr = rb + sr;
      if (gr < rows){
        if constexpr (std::is_same<AT, float>::value){
          const float4* p = (const float4*)(A + (size_t)gr*Kd + k0 + sc);
          float4 v0 = p[0], v1 = p[1], v2 = p[2], v3 = p[3];
          ta0 = (bf16x8){f2s(v0.x),f2s(v0.y),f2s(v0.z),f2s(v0.w), f2s(v1.x),f2s(v1.y),f2s(v1.z),f2s(v1.w)};
          ta1 = (bf16x8){f2s(v2.x),f2s(v2.y),f2s(v2.z),f2s(v2.w), f2s(v3.x),f2s(v3.y),f2s(v3.z),f2s(v3.w)};
        } else {
          const bf16x8* p = (const bf16x8*)((const unsigned short*)A + (size_t)gr*Kd + k0 + sc);
          ta0 = p[0]; ta1 = p[1];
        }
      }
    }
    {
      const float4* p = (const float4*)(W + (size_t)(nb + sr)*Kd + k0 + sc);
      float4 v0 = p[0], v1 = p[1], v2 = p[2], v3 = p[3];
      tb0 = (bf16x8){f2s(v0.x),f2s(v0.y),f2s(v0.z),f2s(v0.w), f2s(v1.x),f2s(v1.y),f2s(v1.z),f2s(v1.w)};
      tb1 = (bf16x8){f2s(v2.x),f2s(v2.y),f2s(v2.z),f2s(v2.w), f2s(v3.x),f2s(v3.y),f2s(v3.z),f2s(v3.w)};
    }
    __syncthreads();   // prior iteration's frag reads complete before overwrite
    *(bf16x8*)&As[sr][sc]     = ta0;
    *(bf16x8*)&As[sr][sc + 8] = ta1;
    *(bf16x8*)&Bs[sr][sc]     = tb0;
    *(bf16x8*)&Bs[sr][sc + 8] = tb1;
    __syncthreads();
    bf16x8 af[4], bf_[4];
    #pragma unroll
    for (int mi = 0; mi < 4; mi++) af[mi]  = *(const bf16x8*)&As[wr + mi*16 + lr][lk*8];
    #pragma unroll
    for (int ni = 0; ni < 4; ni++) bf_[ni] = *(const bf16x8*)&Bs[wc + ni*16 + lr][lk*8];
    #pragma unroll
    for (int mi = 0; mi < 4; mi++)
      #pragma unroll
      for (int ni = 0; ni < 4; ni++)
        acc[mi][ni] = __builtin_amdgcn_mfma_f32_16x16x32_bf16(af[mi], bf_[ni], acc[mi][ni], 0, 0, 0);
  }

  #pragma unroll
  for (int mi = 0; mi < 4; mi++){
    #pragma unroll
    for (int ni = 0; ni < 4; ni++){
      int col = nb + wc + ni*16 + lr;
      float bs = bias[col];
      #pragma unroll
      for (int r = 0; r < 4; r++){
        int row = rb + wr + mi*16 + lk*4 + r;
        if (row < rows){
          float v = acc[mi][ni][r] + bs;
          if (ACT == 1) v = 0.5f*v*(1.0f + erff(v*0.70710678118654752f));
          if constexpr (std::is_same<CT, float>::value) C[(size_t)row*Nc + col] = v;
          else C[(size_t)row*Nc + col] = __float2bfloat16(v);
        }
      }
    }
  }
}

// ==================== row LayerNorm (D=512), optional residual + relu. NO restrict (args may alias). ====================
template<typename XT, typename OT>
__global__ __launch_bounds__(256) void k_ln(const XT* X, const float* R,
                                            const float* g, const float* bt,
                                            OT* out, int relu)
{
  __shared__ float red[4];
  int row = blockIdx.x, t = threadIdx.x;
  size_t base = (size_t)row * 512;
  float x0, x1;
  if constexpr (std::is_same<XT, float>::value){ x0 = X[base + t]; x1 = X[base + t + 256]; }
  else { x0 = b2f(X[base + t]); x1 = b2f(X[base + t + 256]); }
  if (R){ x0 += R[base + t]; x1 += R[base + t + 256]; }
  float v = x0 + x1;
  #pragma unroll
  for (int o = 32; o > 0; o >>= 1) v += __shfl_xor(v, o);
  if ((t & 63) == 0) red[t >> 6] = v;
  __syncthreads();
  float mean = (red[0]+red[1]+red[2]+red[3]) * (1.0f/512.0f);
  float d0 = x0 - mean, d1 = x1 - mean;
  v = d0*d0 + d1*d1;
  #pragma unroll
  for (int o = 32; o > 0; o >>= 1) v += __shfl_xor(v, o);
  __syncthreads();
  if ((t & 63) == 0) red[t >> 6] = v;
  __syncthreads();
  float var = (red[0]+red[1]+red[2]+red[3]) * (1.0f/512.0f);
  float is = 1.0f / sqrtf(var + 1e-5f);
  float y0 = d0*is*g[t] + bt[t];
  float y1 = d1*is*g[t+256] + bt[t+256];
  if (relu){ y0 = fmaxf(y0, 0.0f); y1 = fmaxf(y1, 0.0f); }
  if constexpr (std::is_same<OT, float>::value){ out[base + t] = y0; out[base + t + 256] = y1; }
  else { out[base + t] = __float2bfloat16(y0); out[base + t + 256] = __float2bfloat16(y1); }
}

// ==================== bev transpose chunk [16b, 512, 256] f32 -> [16b*256, 512] bf16 ====================
__global__ void k_bev_tok(const float* __restrict__ bev, bf16* __restrict__ out, int b0){
  __shared__ float tile[32][33];
  int bl = blockIdx.z;
  int b  = b0 + bl;
  int d0 = blockIdx.x * 32;
  int p0 = blockIdx.y * 32;
  int tx = threadIdx.x, ty = threadIdx.y;
  #pragma unroll
  for (int i = 0; i < 4; i++){
    int d = d0 + ty + i*8;
    tile[ty + i*8][tx] = bev[((size_t)b*512 + d)*256 + p0 + tx];
  }
  __syncthreads();
  #pragma unroll
  for (int i = 0; i < 4; i++){
    int p = p0 + ty + i*8;
    out[((size_t)bl*256 + p)*512 + d0 + tx] = __float2bfloat16(tile[tx][ty + i*8]);
  }
}

// ==================== top-K agents + invalid mask ====================
__global__ void k_topk(const float* __restrict__ labels, const float* __restrict__ states,
                       int* __restrict__ idxo, int* __restrict__ invo)
{
  __shared__ float dist[32];
  __shared__ int valid[32];
  int b = blockIdx.x, t = threadIdx.x;
  if (t < 32){
    float lab = labels[b*32 + t];
    float sg = 1.0f / (1.0f + expf(-lab));
    int va = sg > 0.05f;
    float x = states[((size_t)b*32 + t)*8 + 0];
    float y = states[((size_t)b*32 + t)*8 + 1];
    float d = sqrtf(__fadd_rn(__fmul_rn(x,x), __fmul_rn(y,y)));
    dist[t] = va ? d : INFINITY;
    valid[t] = va;
  }
  __syncthreads();
  if (t == 0){
    unsigned used = 0;
    int inv8[8]; int allinv = 1;
    for (int kk = 0; kk < 8; kk++){
      float best = INFINITY; int bi = -1;
      for (int i = 0; i < 32; i++){
        if (used & (1u << i)) continue;
        if (bi < 0 || dist[i] < best){ best = dist[i]; bi = i; }
      }
      used |= 1u << bi;
      idxo[b*8 + kk] = bi;
      inv8[kk] = !valid[bi];
      allinv &= inv8[kk];
    }
    for (int kk = 0; kk < 8; kk++) invo[b*8 + kk] = allinv ? 0 : inv8[kk];
  }
}

// ==================== gather agents f32 -> bf16 [512,512] ====================
__global__ void k_gather(const float* __restrict__ aq, const int* __restrict__ idx, bf16* __restrict__ out)
{
  int rk = blockIdx.x; int b = rk >> 3;
  int src = idx[rk] & 31;
  int t = threadIdx.x;
  size_t sbase = ((size_t)(b*32 + src))*512;
  out[(size_t)rk*512 + t]       = __float2bfloat16(aq[sbase + t]);
  out[(size_t)rk*512 + t + 256] = __float2bfloat16(aq[sbase + t + 256]);
}

// ==================== agent_kv f32 enc -> bf16 [4096,512] ====================
__global__ void k_agentkv(const float* __restrict__ enc, const float* __restrict__ step_e,
                          const float* __restrict__ role_e, bf16* __restrict__ out)
{
  int row = blockIdx.x;
  int t8 = row & 7; int bk = row >> 3;
  int tx = threadIdx.x;
  #pragma unroll
  for (int j = 0; j < 2; j++){
    int d = tx + j*256;
    out[(size_t)row*512 + d] = __float2bfloat16((enc[(size_t)bk*512 + d] + step_e[t8*512 + d]) + role_e[512 + d]);
  }
}

// ==================== sequential codebook NN scan -> tokens [B,T] ====================
__global__ __launch_bounds__(64) void k_cbscan(const float* __restrict__ gt, const float* __restrict__ cb,
                                               int* __restrict__ toks)
{
  __shared__ float cbx[512], cby[512];
  int b = blockIdx.x;
  int l = threadIdx.x;
  #pragma unroll
  for (int i = 0; i < 8; i++){
    int v = l + i*64;
    cbx[v] = cb[v*2 + 0];
    cby[v] = cb[v*2 + 1];
  }
  __syncthreads();
  float ax = 0.0f, ay = 0.0f;
  for (int t = 0; t < 8; t++){
    float px = gt[(b*8 + t)*3 + 0];
    float py = gt[(b*8 + t)*3 + 1];
    float bestv = INFINITY; int besti = 0;
    #pragma unroll
    for (int i = 0; i < 8; i++){
      int v = l*8 + i;
      float dx = __fsub_rn(__fadd_rn(ax, cbx[v]), px);
      float dy = __fsub_rn(__fadd_rn(ay, cby[v]), py);
      float d = __fadd_rn(__fmul_rn(dx,dx), __fmul_rn(dy,dy));
      if (d < bestv || (d == bestv && v < besti)){ bestv = d; besti = v; }
    }
    #pragma unroll
    for (int o = 32; o > 0; o >>= 1){
      float ov = __shfl_xor(bestv, o);
      int oi = __shfl_xor(besti, o);
      if (ov < bestv || (ov == bestv && oi < besti)){ bestv = ov; besti = oi; }
    }
    ax = __fadd_rn(ax, cbx[besti]);
    ay = __fadd_rn(ay, cby[besti]);
    if (l == 0) toks[b*8 + t] = besti;
  }
}

// ==================== teacher-forced embedding -> egoq f32 ====================
__global__ void k_embed(const int* __restrict__ toks, const float* __restrict__ ebase,
                        const float* __restrict__ tok_emb, const float* __restrict__ step_e,
                        const float* __restrict__ mode_e, const float* __restrict__ role_e,
                        const float* __restrict__ bos_e, float* __restrict__ out)
{
  int row = blockIdx.x;
  int t = row & 7; int bm = row >> 3; int m = bm % 20; int b = bm / 20;
  int tok = (t == 0) ? 0 : (toks[b*8 + t - 1] & 511);
  int tx = threadIdx.x;
  #pragma unroll
  for (int j = 0; j < 2; j++){
    int d = tx + j*256;
    float base = (t == 0) ? (bos_e[d] + ebase[(size_t)b*512 + d])
                          : tok_emb[(size_t)tok*512 + d];
    out[(size_t)row*512 + d] = ((base + step_e[t*512 + d]) + role_e[d]) + mode_e[m*512 + d];
  }
}

// ==================== temporal causal attention (QKV bf16 [rows,1536] -> O bf16) ====================
__global__ __launch_bounds__(64) void k_tattn(const bf16* __restrict__ QKV, bf16* __restrict__ O)
{
  __shared__ float q[8][65], k[8][65], v[8][65], w[8][9];
  int h = blockIdx.x & 7; int bm = blockIdx.x >> 3;
  int l = threadIdx.x;
  for (int t = 0; t < 8; t++){
    size_t base = ((size_t)(bm*8 + t))*1536 + h*64 + l;
    q[t][l] = b2f(QKV[base]);
    k[t][l] = b2f(QKV[base + 512]);
    v[t][l] = b2f(QKV[base + 1024]);
  }
  __syncthreads();
  int tq = l >> 3, tk = l & 7;
  float s = -INFINITY;
  if (tk <= tq){
    float acc = 0.0f;
    #pragma unroll
    for (int e = 0; e < 64; e++) acc += q[tq][e]*k[tk][e];
    s = acc * 0.125f;
  }
  float mx = s;
  #pragma unroll
  for (int o = 1; o < 8; o <<= 1) mx = fmaxf(mx, __shfl_xor(mx, o));
  float ex = (tk <= tq) ? expf(s - mx) : 0.0f;
  float sm = ex;
  #pragma unroll
  for (int o = 1; o < 8; o <<= 1) sm += __shfl_xor(sm, o);
  w[tq][tk] = ex / sm;
  __syncthreads();
  #pragma unroll
  for (int t2 = 0; t2 < 8; t2++){
    float acc = 0.0f;
    #pragma unroll
    for (int tk2 = 0; tk2 < 8; tk2++) acc += w[t2][tk2]*v[tk2][l];
    O[((size_t)(bm*8 + t2))*512 + h*64 + l] = __float2bfloat16(acc);
  }
}

// ==================== ego-to-agent cross-attention (bf16 Q/K/V/O) ====================
__global__ __launch_bounds__(64) void k_eattn(const bf16* __restrict__ Q, const bf16* __restrict__ Ka,
                                              const bf16* __restrict__ Va, const int* __restrict__ inv,
                                              bf16* __restrict__ O, int row0)
{
  int blk = blockIdx.x;
  int h = blockIdx.y;
  int grow = row0 + blk;
  int t = grow & 7;
  int b = grow / 160;
  int l = threadIdx.x;
  size_t qoff = (size_t)blk*512 + h*64 + l;
  float q = b2f(Q[qoff]);
  float s[8];
  #pragma unroll
  for (int k = 0; k < 8; k++){
    float p = q * b2f(Ka[((size_t)((b*8 + k)*8 + t))*512 + h*64 + l]);
    #pragma unroll
    for (int o = 32; o > 0; o >>= 1) p += __shfl_xor(p, o);
    s[k] = p * 0.125f;
  }
  float mx = -INFINITY;
  #pragma unroll
  for (int k = 0; k < 8; k++){
    if (inv[b*8 + k]) s[k] = -INFINITY;
    mx = fmaxf(mx, s[k]);
  }
  float sum = 0.0f, w[8];
  #pragma unroll
  for (int k = 0; k < 8; k++){ w[k] = expf(s[k] - mx); sum += w[k]; }
  float rs = 1.0f / sum;
  float acc = 0.0f;
  #pragma unroll
  for (int k = 0; k < 8; k++) acc += (w[k]*rs) * b2f(Va[((size_t)((b*8 + k)*8 + t))*512 + h*64 + l]);
  O[qoff] = __float2bfloat16(acc);
}

// ==================== BEV cross-attention: Q/O [2560,512] bf16, K/V [4096,512] bf16; grid (16,8,4) ====================
__global__ __launch_bounds__(256) void k_vattn(const bf16* __restrict__ Q, const bf16* __restrict__ Kb,
                                               const bf16* __restrict__ Vb, bf16* __restrict__ O)
{
  __shared__ unsigned short Ks[256][66];
  __shared__ float qs[4][64];
  __shared__ float wgt[4][256];
  __shared__ float part[4][4][64];
  __shared__ float red[4][4];
  int bl = blockIdx.x;          // local b (0..15)
  int h = blockIdx.y, qc = blockIdx.z;
  int tid = threadIdx.x;
  const unsigned short* Kraw = (const unsigned short*)Kb;
  for (int i = 0; i < 64; i++){
    int idx = i*256 + tid;
    int p = idx >> 6, e = idx & 63;
    Ks[p][e] = Kraw[((size_t)(bl*256 + p))*512 + h*64 + e];
  }
  __syncthreads();
  int g = tid >> 6, e = tid & 63;
  for (int q0 = qc*40; q0 < qc*40 + 40; q0 += 4){
    {
      int q = tid >> 6; int ee = tid & 63;
      qs[q][ee] = b2f(Q[((size_t)(bl*160 + q0 + q))*512 + h*64 + ee]);
    }
    __syncthreads();
    float s[4] = {0,0,0,0};
    #pragma unroll 8
    for (int e2 = 0; e2 < 64; e2 += 2){
      float k0 = u2f(Ks[tid][e2]);
      float k1 = u2f(Ks[tid][e2+1]);
      #pragma unroll
      for (int q = 0; q < 4; q++) s[q] += qs[q][e2]*k0 + qs[q][e2+1]*k1;
    }
    #pragma unroll
    for (int q = 0; q < 4; q++){
      float sv = s[q]*0.125f;
      s[q] = sv;
      float mx = sv;
      #pragma unroll
      for (int o = 32; o > 0; o >>= 1) mx = fmaxf(mx, __shfl_xor(mx, o));
      if ((tid & 63) == 0) red[q][tid >> 6] = mx;
    }
    __syncthreads();
    float ex[4];
    #pragma unroll
    for (int q = 0; q < 4; q++){
      float mx = fmaxf(fmaxf(red[q][0],red[q][1]), fmaxf(red[q][2],red[q][3]));
      ex[q] = expf(s[q] - mx);
    }
    __syncthreads();
    #pragma unroll
    for (int q = 0; q < 4; q++){
      float sm = ex[q];
      #pragma unroll
      for (int o = 32; o > 0; o >>= 1) sm += __shfl_xor(sm, o);
      if ((tid & 63) == 0) red[q][tid >> 6] = sm;
    }
    __syncthreads();
    #pragma unroll
    for (int q = 0; q < 4; q++){
      float sm = red[q][0]+red[q][1]+red[q][2]+red[q][3];
      wgt[q][tid] = ex[q] / sm;
    }
    __syncthreads();
    float acc[4] = {0,0,0,0};
    for (int j = 0; j < 64; j++){
      int p = g*64 + j;
      float v = b2f(Vb[((size_t)(bl*256 + p))*512 + h*64 + e]);
      #pragma unroll
      for (int q = 0; q < 4; q++) acc[q] += wgt[q][p]*v;
    }
    #pragma unroll
    for (int q = 0; q < 4; q++) part[g][q][e] = acc[q];
    __syncthreads();
    {
      int q = tid >> 6; int ee = tid & 63;
      float o = part[0][q][ee]+part[1][q][ee]+part[2][q][ee]+part[3][q][ee];
      O[((size_t)(bl*160 + q0 + q))*512 + h*64 + ee] = __float2bfloat16(o);
    }
    __syncthreads();
  }
}

// ==================== f32 rows -> bf16 rows ====================
__global__ void k_cvtrows(const float* __restrict__ src, bf16* __restrict__ dst){
  int r = blockIdx.x, t = threadIdx.x;
  dst[(size_t)r*512 + t]       = __float2bfloat16(src[(size_t)r*512 + t]);
  dst[(size_t)r*512 + t + 256] = __float2bfloat16(src[(size_t)r*512 + t + 256]);
}

extern "C" void kernel_launch(void* const* d_in, const int* in_sizes, int n_in,
                              void* d_out, int out_size, void* d_ws, size_t ws_size,
                              hipStream_t stream)
{
  (void)in_sizes; (void)n_in; (void)out_size;
  const float* ego_query    = (const float*)d_in[0];
  const float* agents_query = (const float*)d_in[1];
  const float* bev_feature  = (const float*)d_in[2];
  const float* agent_states = (const float*)d_in[3];
  const float* agent_labels = (const float*)d_in[4];
  const float* gt_traj      = (const float*)d_in[5];
  const float* codebook     = (const float*)d_in[6];
  const float* ego_ctx_w    = (const float*)d_in[7];
  const float* ego_ctx_b    = (const float*)d_in[8];
  const float* ego_ctx_g    = (const float*)d_in[9];
  const float* ego_ctx_beta = (const float*)d_in[10];
  const float* bevproj_w    = (const float*)d_in[11];
  const float* bevproj_b    = (const float*)d_in[12];
  const float* bevproj_g    = (const float*)d_in[13];
  const float* bevproj_beta = (const float*)d_in[14];
  const float* agent_w      = (const float*)d_in[15];
  const float* agent_b      = (const float*)d_in[16];
  const float* agent_g      = (const float*)d_in[17];
  const float* agent_beta   = (const float*)d_in[18];
  const float* tok_emb      = (const float*)d_in[19];
  const float* step_e       = (const float*)d_in[20];
  const float* mode_e       = (const float*)d_in[21];
  const float* role_e       = (const float*)d_in[22];
  const float* bos_e        = (const float*)d_in[23];
  const float* t_qkv_w      = (const float*)d_in[24];
  const float* t_qkv_b      = (const float*)d_in[25];
  const float* t_out_w      = (const float*)d_in[26];
  const float* t_out_b      = (const float*)d_in[27];
  const float* t_g          = (const float*)d_in[28];
  const float* t_beta       = (const float*)d_in[29];
  const float* e_qkv_w      = (const float*)d_in[30];
  const float* e_qkv_b      = (const float*)d_in[31];
  const float* e_out_w      = (const float*)d_in[32];
  const float* e_out_b      = (const float*)d_in[33];
  const float* e_g          = (const float*)d_in[34];
  const float* e_beta       = (const float*)d_in[35];
  const float* v_qkv_w      = (const float*)d_in[36];
  const float* v_qkv_b      = (const float*)d_in[37];
  const float* v_out_w      = (const float*)d_in[38];
  const float* v_out_b      = (const float*)d_in[39];
  const float* v_g          = (const float*)d_in[40];
  const float* v_beta       = (const float*)d_in[41];
  const float* ffn_w1       = (const float*)d_in[42];
  const float* ffn_b1       = (const float*)d_in[43];
  const float* ffn_w2       = (const float*)d_in[44];
  const float* ffn_b2       = (const float*)d_in[45];
  const float* ffn_g        = (const float*)d_in[46];
  const float* ffn_beta     = (const float*)d_in[47];
  const float* head_w       = (const float*)d_in[48];
  const float* head_b       = (const float*)d_in[49];

  // ---- workspace (byte offsets), total 42,080,256 B ----
  char* WB = (char*)d_ws;
  bf16* akv   = (bf16*)(WB + 0);           // [4096,512] bf16
  float* ebase= (float*)(WB + 4194304);    // [64,512] f32
  bf16* A_h   = (bf16*)(WB + 4325376);     // [2560,2048] bf16 (QKV/hid/bev-raw/head-in [10240,512])
  bf16* A_k   = (bf16*)(WB + 14811136);    // [4096,512] bf16
  bf16* A_v   = (bf16*)(WB + 19005440);    // [4096,512] bf16
  bf16* A_t   = (bf16*)(WB + 23199744);    // [4096,512] bf16 (bev tokens post-LN)
  bf16* A_b   = (bf16*)(WB + 27394048);    // [4096,512] bf16 (bevproj pre-LN)
  bf16* A_q   = (bf16*)(WB + 31588352);    // [2560,512] bf16
  bf16* A_o   = (bf16*)(WB + 34209792);    // [2560,512] bf16
  float* A_x  = (float*)(WB + 36831232);   // [2560,512] f32
  int* toks   = (int*)(WB + 42074112);
  int* idxb   = toks + 512;
  int* invb   = idxb + 512;

  const size_t NEEDED = 42080256;
  if (ws_size < NEEDED) return;

  float* egoq = (float*)d_out;   // [10240,512] f32 residual stream lives in d_out (round-4-proven pattern)

  #define GEMM(AT,CT,ACT,Ap,Wp,Bp,Cp,R,K,N) \
    k_gemm_mfma<AT,CT,ACT><<<dim3(((R)+127)/128,(N)/128),256,0,stream>>>(Ap,Wp,Bp,Cp,R,K,N)

  // --- ego base ---
  GEMM(float,float,0, ego_query, ego_ctx_w, ego_ctx_b, A_x, 64, 512, 512);
  k_ln<float,float><<<64, 256, 0, stream>>>(A_x, nullptr, ego_ctx_g, ego_ctx_beta, ebase, 1);

  // --- agents ---
  k_topk<<<64, 64, 0, stream>>>(agent_labels, agent_states, idxb, invb);
  k_gather<<<512, 256, 0, stream>>>(agents_query, idxb, A_h);
  GEMM(bf16,float,0, A_h, agent_w, agent_b, A_x, 512, 512, 512);
  k_ln<float,float><<<512, 256, 0, stream>>>(A_x, nullptr, agent_g, agent_beta, A_x, 1);
  k_agentkv<<<4096, 256, 0, stream>>>(A_x, step_e, role_e, akv);

  // --- tokens + embedding ---
  k_cbscan<<<64, 64, 0, stream>>>(gt_traj, codebook, toks);
  k_embed<<<10240, 256, 0, stream>>>(toks, ebase, tok_emb, step_e, mode_e, role_e, bos_e, egoq);

  for (int i = 0; i < 2; i++){
    // ---- temporal self-attention (4 chunks x 2560 rows) ----
    for (int c = 0; c < 4; c++){
      float* eg = egoq + (size_t)c*2560*512;
      GEMM(float,bf16,0, eg, t_qkv_w + (size_t)i*786432, t_qkv_b + i*1536, A_h, 2560, 512, 1536);
      k_tattn<<<2560, 64, 0, stream>>>(A_h, A_o);
      GEMM(bf16,float,0, A_o, t_out_w + (size_t)i*262144, t_out_b + i*512, A_x, 2560, 512, 512);
      k_ln<float,float><<<2560, 256, 0, stream>>>(A_x, eg, t_g + i*512, t_beta + i*512, eg, 0);
    }
    // ---- ego-to-agent cross-attention ----
    {
      const float* eqw = e_qkv_w + (size_t)i*786432;
      const float* eqb = e_qkv_b + i*1536;
      GEMM(bf16,bf16,0, akv, eqw + 262144, eqb + 512,  A_k, 4096, 512, 512);
      GEMM(bf16,bf16,0, akv, eqw + 524288, eqb + 1024, A_v, 4096, 512, 512);
      for (int c = 0; c < 4; c++){
        float* eg = egoq + (size_t)c*2560*512;
        GEMM(float,bf16,0, eg, eqw, eqb, A_q, 2560, 512, 512);
        k_eattn<<<dim3(2560, 8), 64, 0, stream>>>(A_q, A_k, A_v, invb, A_o, c*2560);
        GEMM(bf16,float,0, A_o, e_out_w + (size_t)i*262144, e_out_b + i*512, A_x, 2560, 512, 512);
        k_ln<float,float><<<2560, 256, 0, stream>>>(A_x, eg, e_g + i*512, e_beta + i*512, eg, 0);
      }
    }
    // ---- BEV cross-attention (4 groups x 16 batches) ----
    {
      const float* vqw = v_qkv_w + (size_t)i*786432;
      const float* vqb = v_qkv_b + i*1536;
      for (int gidx = 0; gidx < 4; gidx++){
        float* eg = egoq + (size_t)gidx*2560*512;
        k_bev_tok<<<dim3(16, 8, 16), dim3(32, 8), 0, stream>>>(bev_feature, A_h, gidx*16);
        GEMM(bf16,bf16,0, A_h, bevproj_w, bevproj_b, A_b, 4096, 512, 512);
        k_ln<bf16,bf16><<<4096, 256, 0, stream>>>(A_b, nullptr, bevproj_g, bevproj_beta, A_t, 1);
        GEMM(bf16,bf16,0, A_t, vqw + 262144, vqb + 512,  A_k, 4096, 512, 512);
        GEMM(bf16,bf16,0, A_t, vqw + 524288, vqb + 1024, A_v, 4096, 512, 512);
        GEMM(float,bf16,0, eg, vqw, vqb, A_q, 2560, 512, 512);
        k_vattn<<<dim3(16, 8, 4), 256, 0, stream>>>(A_q, A_k, A_v, A_o);
        GEMM(bf16,float,0, A_o, v_out_w + (size_t)i*262144, v_out_b + i*512, A_x, 2560, 512, 512);
        k_ln<float,float><<<2560, 256, 0, stream>>>(A_x, eg, v_g + i*512, v_beta + i*512, eg, 0);
      }
    }
    // ---- FFN (4 chunks, GELU fused into ffn1 epilogue) ----
    for (int c = 0; c < 4; c++){
      float* eg = egoq + (size_t)c*2560*512;
      GEMM(float,bf16,1, eg, ffn_w1 + (size_t)i*1048576, ffn_b1 + i*2048, A_h, 2560, 512, 2048);
      GEMM(bf16,float,0, A_h, ffn_w2 + (size_t)i*1048576, ffn_b2 + i*512, A_x, 2560, 2048, 512);
      k_ln<float,float><<<2560, 256, 0, stream>>>(A_x, eg, ffn_g + i*512, ffn_beta + i*512, eg, 0);
    }
  }

  // --- head: convert ALL rows to bf16 (reads d_out fully), then one GEMM writes d_out once ---
  k_cvtrows<<<10240, 256, 0, stream>>>(egoq, A_h);
  GEMM(bf16,float,0, A_h, head_w, head_b, (float*)d_out, 10240, 512, 512);
  #undef GEMM
}

// Round 7
// 2595.613 us; speedup vs baseline: 3.0641x; 1.3917x over previous
//
#include <hip/hip_runtime.h>
#include <hip/hip_bf16.h>
#include <math.h>
#include <type_traits>

typedef __hip_bfloat16 bf16;
typedef __attribute__((ext_vector_type(8))) short bf16x8;
typedef __attribute__((ext_vector_type(4))) float f32x4;
typedef __attribute__((ext_vector_type(4))) unsigned short us4;

__device__ __forceinline__ float b2f(bf16 x){ return __bfloat162float(x); }
__device__ __forceinline__ short f2s(float f){
  bf16 h = __float2bfloat16(f);
  short s; __builtin_memcpy(&s, &h, 2); return s;
}
__device__ __forceinline__ float u2f(unsigned short u){ union { unsigned int i; float f; } z; z.i = ((unsigned int)u) << 16; return z.f; }

// ==================== MFMA GEMM: C[r,n] = act( sum_k A[r,k]*W[n,k] + bias[n] [+ R] ) ====================
// 128xBN tile (BN=128 or 64), BK=32, 4 waves, 16x16x32 bf16 MFMA, fp32 accum.
// RES=1: adds Rres (fp32, same layout as C; may alias C). rows guarded; Kd%32==0; Nc%BN==0.
template<typename AT, typename CT, int ACT, int BN, int RES>
__global__ __launch_bounds__(256) void k_gemm_mfma(const AT* __restrict__ A, const float* __restrict__ W,
                                                   const float* __restrict__ bias, CT* C,
                                                   const float* Rres, int rows, int Kd, int Nc)
{
  __shared__ short As[128][40];   // 80 B row stride: 16B-aligned, 2-way bank alias (free)
  __shared__ short Bs[BN][40];
  constexpr int NI = BN / 32;     // n-frags per wave
  int rb = blockIdx.x * 128, nb = blockIdx.y * BN;
  int tid = threadIdx.x;
  int l = tid & 63, w = tid >> 6;
  int wr = (w >> 1) * 64, wc = (w & 1) * (BN/2);
  int lr = l & 15, lk = l >> 4;
  f32x4 acc[4][NI];
  #pragma unroll
  for (int i = 0; i < 4; i++)
    #pragma unroll
    for (int j = 0; j < NI; j++)
      acc[i][j] = (f32x4){0.f, 0.f, 0.f, 0.f};
  int sr = tid >> 1;            // A staging row 0..127
  int sc = (tid & 1) * 16;      // staging col 0 or 16
  bool doB = (BN == 128) || (tid < 128);

  for (int k0 = 0; k0 < Kd; k0 += 32){
    bf16x8 ta0 = {0,0,0,0,0,0,0,0}, ta1 = {0,0,0,0,0,0,0,0};
    bf16x8 tb0, tb1;
    {
      int gr = rb + sr;
      if (gr < rows){
        if constexpr (std::is_same<AT, float>::value){
          const float4* p = (const float4*)(A + (size_t)gr*Kd + k0 + sc);
          float4 v0 = p[0], v1 = p[1], v2 = p[2], v3 = p[3];
          ta0 = (bf16x8){f2s(v0.x),f2s(v0.y),f2s(v0.z),f2s(v0.w), f2s(v1.x),f2s(v1.y),f2s(v1.z),f2s(v1.w)};
          ta1 = (bf16x8){f2s(v2.x),f2s(v2.y),f2s(v2.z),f2s(v2.w), f2s(v3.x),f2s(v3.y),f2s(v3.z),f2s(v3.w)};
        } else {
          const bf16x8* p = (const bf16x8*)((const unsigned short*)A + (size_t)gr*Kd + k0 + sc);
          ta0 = p[0]; ta1 = p[1];
        }
      }
    }
    if (doB){
      const float4* p = (const float4*)(W + (size_t)(nb + sr)*Kd + k0 + sc);
      float4 v0 = p[0], v1 = p[1], v2 = p[2], v3 = p[3];
      tb0 = (bf16x8){f2s(v0.x),f2s(v0.y),f2s(v0.z),f2s(v0.w), f2s(v1.x),f2s(v1.y),f2s(v1.z),f2s(v1.w)};
      tb1 = (bf16x8){f2s(v2.x),f2s(v2.y),f2s(v2.z),f2s(v2.w), f2s(v3.x),f2s(v3.y),f2s(v3.z),f2s(v3.w)};
    }
    __syncthreads();   // prior iteration's frag reads complete before overwrite
    *(bf16x8*)&As[sr][sc]     = ta0;
    *(bf16x8*)&As[sr][sc + 8] = ta1;
    if (doB){
      *(bf16x8*)&Bs[sr][sc]     = tb0;
      *(bf16x8*)&Bs[sr][sc + 8] = tb1;
    }
    __syncthreads();
    bf16x8 af[4], bf_[NI];
    #pragma unroll
    for (int mi = 0; mi < 4; mi++) af[mi]  = *(const bf16x8*)&As[wr + mi*16 + lr][lk*8];
    #pragma unroll
    for (int ni = 0; ni < NI; ni++) bf_[ni] = *(const bf16x8*)&Bs[wc + ni*16 + lr][lk*8];
    #pragma unroll
    for (int mi = 0; mi < 4; mi++)
      #pragma unroll
      for (int ni = 0; ni < NI; ni++)
        acc[mi][ni] = __builtin_amdgcn_mfma_f32_16x16x32_bf16(af[mi], bf_[ni], acc[mi][ni], 0, 0, 0);
  }

  #pragma unroll
  for (int mi = 0; mi < 4; mi++){
    #pragma unroll
    for (int ni = 0; ni < NI; ni++){
      int col = nb + wc + ni*16 + lr;
      float bs = bias[col];
      #pragma unroll
      for (int r = 0; r < 4; r++){
        int row = rb + wr + mi*16 + lk*4 + r;
        if (row < rows){
          float v = acc[mi][ni][r] + bs;
          if (RES) v += Rres[(size_t)row*Nc + col];
          if (ACT == 1) v = 0.5f*v*(1.0f + erff(v*0.70710678118654752f));
          if constexpr (std::is_same<CT, float>::value) C[(size_t)row*Nc + col] = v;
          else C[(size_t)row*Nc + col] = __float2bfloat16(v);
        }
      }
    }
  }
}

// ==================== row LayerNorm (D=512), optional residual + relu. NO restrict (may run in place). ====================
template<typename XT, typename OT>
__global__ __launch_bounds__(256) void k_ln(const XT* X, const float* R,
                                            const float* g, const float* bt,
                                            OT* out, int relu)
{
  __shared__ float red[4];
  int row = blockIdx.x, t = threadIdx.x;
  size_t base = (size_t)row * 512;
  float x0, x1;
  if constexpr (std::is_same<XT, float>::value){ x0 = X[base + t]; x1 = X[base + t + 256]; }
  else { x0 = b2f(X[base + t]); x1 = b2f(X[base + t + 256]); }
  if (R){ x0 += R[base + t]; x1 += R[base + t + 256]; }
  float v = x0 + x1;
  #pragma unroll
  for (int o = 32; o > 0; o >>= 1) v += __shfl_xor(v, o);
  if ((t & 63) == 0) red[t >> 6] = v;
  __syncthreads();
  float mean = (red[0]+red[1]+red[2]+red[3]) * (1.0f/512.0f);
  float d0 = x0 - mean, d1 = x1 - mean;
  v = d0*d0 + d1*d1;
  #pragma unroll
  for (int o = 32; o > 0; o >>= 1) v += __shfl_xor(v, o);
  __syncthreads();
  if ((t & 63) == 0) red[t >> 6] = v;
  __syncthreads();
  float var = (red[0]+red[1]+red[2]+red[3]) * (1.0f/512.0f);
  float is = 1.0f / sqrtf(var + 1e-5f);
  float y0 = d0*is*g[t] + bt[t];
  float y1 = d1*is*g[t+256] + bt[t+256];
  if (relu){ y0 = fmaxf(y0, 0.0f); y1 = fmaxf(y1, 0.0f); }
  if constexpr (std::is_same<OT, float>::value){ out[base + t] = y0; out[base + t + 256] = y1; }
  else { out[base + t] = __float2bfloat16(y0); out[base + t + 256] = __float2bfloat16(y1); }
}

// ==================== bev transpose chunk [16b, 512, 256] f32 -> [16b*256, 512] bf16 ====================
__global__ void k_bev_tok(const float* __restrict__ bev, bf16* __restrict__ out, int b0){
  __shared__ float tile[32][33];
  int bl = blockIdx.z;
  int b  = b0 + bl;
  int d0 = blockIdx.x * 32;
  int p0 = blockIdx.y * 32;
  int tx = threadIdx.x, ty = threadIdx.y;
  #pragma unroll
  for (int i = 0; i < 4; i++){
    int d = d0 + ty + i*8;
    tile[ty + i*8][tx] = bev[((size_t)b*512 + d)*256 + p0 + tx];
  }
  __syncthreads();
  #pragma unroll
  for (int i = 0; i < 4; i++){
    int p = p0 + ty + i*8;
    out[((size_t)bl*256 + p)*512 + d0 + tx] = __float2bfloat16(tile[tx][ty + i*8]);
  }
}

// ==================== top-K agents + invalid mask ====================
__global__ void k_topk(const float* __restrict__ labels, const float* __restrict__ states,
                       int* __restrict__ idxo, int* __restrict__ invo)
{
  __shared__ float dist[32];
  __shared__ int valid[32];
  int b = blockIdx.x, t = threadIdx.x;
  if (t < 32){
    float lab = labels[b*32 + t];
    float sg = 1.0f / (1.0f + expf(-lab));
    int va = sg > 0.05f;
    float x = states[((size_t)b*32 + t)*8 + 0];
    float y = states[((size_t)b*32 + t)*8 + 1];
    float d = sqrtf(__fadd_rn(__fmul_rn(x,x), __fmul_rn(y,y)));
    dist[t] = va ? d : INFINITY;
    valid[t] = va;
  }
  __syncthreads();
  if (t == 0){
    unsigned used = 0;
    int inv8[8]; int allinv = 1;
    for (int kk = 0; kk < 8; kk++){
      float best = INFINITY; int bi = -1;
      for (int i = 0; i < 32; i++){
        if (used & (1u << i)) continue;
        if (bi < 0 || dist[i] < best){ best = dist[i]; bi = i; }
      }
      used |= 1u << bi;
      idxo[b*8 + kk] = bi;
      inv8[kk] = !valid[bi];
      allinv &= inv8[kk];
    }
    for (int kk = 0; kk < 8; kk++) invo[b*8 + kk] = allinv ? 0 : inv8[kk];
  }
}

// ==================== gather agents f32 -> bf16 [512,512] ====================
__global__ void k_gather(const float* __restrict__ aq, const int* __restrict__ idx, bf16* __restrict__ out)
{
  int rk = blockIdx.x; int b = rk >> 3;
  int src = idx[rk] & 31;
  int t = threadIdx.x;
  size_t sbase = ((size_t)(b*32 + src))*512;
  out[(size_t)rk*512 + t]       = __float2bfloat16(aq[sbase + t]);
  out[(size_t)rk*512 + t + 256] = __float2bfloat16(aq[sbase + t + 256]);
}

// ==================== agent_kv f32 enc -> bf16 [4096,512] ====================
__global__ void k_agentkv(const float* __restrict__ enc, const float* __restrict__ step_e,
                          const float* __restrict__ role_e, bf16* __restrict__ out)
{
  int row = blockIdx.x;
  int t8 = row & 7; int bk = row >> 3;
  int tx = threadIdx.x;
  #pragma unroll
  for (int j = 0; j < 2; j++){
    int d = tx + j*256;
    out[(size_t)row*512 + d] = __float2bfloat16((enc[(size_t)bk*512 + d] + step_e[t8*512 + d]) + role_e[512 + d]);
  }
}

// ==================== sequential codebook NN scan -> tokens [B,T] ====================
__global__ __launch_bounds__(64) void k_cbscan(const float* __restrict__ gt, const float* __restrict__ cb,
                                               int* __restrict__ toks)
{
  __shared__ float cbx[512], cby[512];
  int b = blockIdx.x;
  int l = threadIdx.x;
  #pragma unroll
  for (int i = 0; i < 8; i++){
    int v = l + i*64;
    cbx[v] = cb[v*2 + 0];
    cby[v] = cb[v*2 + 1];
  }
  __syncthreads();
  float ax = 0.0f, ay = 0.0f;
  for (int t = 0; t < 8; t++){
    float px = gt[(b*8 + t)*3 + 0];
    float py = gt[(b*8 + t)*3 + 1];
    float bestv = INFINITY; int besti = 0;
    #pragma unroll
    for (int i = 0; i < 8; i++){
      int v = l*8 + i;
      float dx = __fsub_rn(__fadd_rn(ax, cbx[v]), px);
      float dy = __fsub_rn(__fadd_rn(ay, cby[v]), py);
      float d = __fadd_rn(__fmul_rn(dx,dx), __fmul_rn(dy,dy));
      if (d < bestv || (d == bestv && v < besti)){ bestv = d; besti = v; }
    }
    #pragma unroll
    for (int o = 32; o > 0; o >>= 1){
      float ov = __shfl_xor(bestv, o);
      int oi = __shfl_xor(besti, o);
      if (ov < bestv || (ov == bestv && oi < besti)){ bestv = ov; besti = oi; }
    }
    ax = __fadd_rn(ax, cbx[besti]);
    ay = __fadd_rn(ay, cby[besti]);
    if (l == 0) toks[b*8 + t] = besti;
  }
}

// ==================== teacher-forced embedding -> egoq f32 ====================
__global__ void k_embed(const int* __restrict__ toks, const float* __restrict__ ebase,
                        const float* __restrict__ tok_emb, const float* __restrict__ step_e,
                        const float* __restrict__ mode_e, const float* __restrict__ role_e,
                        const float* __restrict__ bos_e, float* __restrict__ out)
{
  int row = blockIdx.x;
  int t = row & 7; int bm = row >> 3; int m = bm % 20; int b = bm / 20;
  int tok = (t == 0) ? 0 : (toks[b*8 + t - 1] & 511);
  int tx = threadIdx.x;
  #pragma unroll
  for (int j = 0; j < 2; j++){
    int d = tx + j*256;
    float base = (t == 0) ? (bos_e[d] + ebase[(size_t)b*512 + d])
                          : tok_emb[(size_t)tok*512 + d];
    out[(size_t)row*512 + d] = ((base + step_e[t*512 + d]) + role_e[d]) + mode_e[m*512 + d];
  }
}

// ==================== temporal causal attention (QKV bf16 [rows,1536] -> O bf16) ====================
__global__ __launch_bounds__(64) void k_tattn(const bf16* __restrict__ QKV, bf16* __restrict__ O)
{
  __shared__ float q[8][65], k[8][65], v[8][65], w[8][9];
  int h = blockIdx.x & 7; int bm = blockIdx.x >> 3;
  int l = threadIdx.x;
  for (int t = 0; t < 8; t++){
    size_t base = ((size_t)(bm*8 + t))*1536 + h*64 + l;
    q[t][l] = b2f(QKV[base]);
    k[t][l] = b2f(QKV[base + 512]);
    v[t][l] = b2f(QKV[base + 1024]);
  }
  __syncthreads();
  int tq = l >> 3, tk = l & 7;
  float s = -INFINITY;
  if (tk <= tq){
    float acc = 0.0f;
    #pragma unroll
    for (int e = 0; e < 64; e++) acc += q[tq][e]*k[tk][e];
    s = acc * 0.125f;
  }
  float mx = s;
  #pragma unroll
  for (int o = 1; o < 8; o <<= 1) mx = fmaxf(mx, __shfl_xor(mx, o));
  float ex = (tk <= tq) ? expf(s - mx) : 0.0f;
  float sm = ex;
  #pragma unroll
  for (int o = 1; o < 8; o <<= 1) sm += __shfl_xor(sm, o);
  w[tq][tk] = ex / sm;
  __syncthreads();
  #pragma unroll
  for (int t2 = 0; t2 < 8; t2++){
    float acc = 0.0f;
    #pragma unroll
    for (int tk2 = 0; tk2 < 8; tk2++) acc += w[t2][tk2]*v[tk2][l];
    O[((size_t)(bm*8 + t2))*512 + h*64 + l] = __float2bfloat16(acc);
  }
}

// ==================== ego-to-agent cross-attention (bf16 Q/K/V/O) ====================
__global__ __launch_bounds__(64) void k_eattn(const bf16* __restrict__ Q, const bf16* __restrict__ Ka,
                                              const bf16* __restrict__ Va, const int* __restrict__ inv,
                                              bf16* __restrict__ O, int row0)
{
  int blk = blockIdx.x;
  int h = blockIdx.y;
  int grow = row0 + blk;
  int t = grow & 7;
  int b = grow / 160;
  int l = threadIdx.x;
  size_t qoff = (size_t)blk*512 + h*64 + l;
  float q = b2f(Q[qoff]);
  float s[8];
  #pragma unroll
  for (int k = 0; k < 8; k++){
    float p = q * b2f(Ka[((size_t)((b*8 + k)*8 + t))*512 + h*64 + l]);
    #pragma unroll
    for (int o = 32; o > 0; o >>= 1) p += __shfl_xor(p, o);
    s[k] = p * 0.125f;
  }
  float mx = -INFINITY;
  #pragma unroll
  for (int k = 0; k < 8; k++){
    if (inv[b*8 + k]) s[k] = -INFINITY;
    mx = fmaxf(mx, s[k]);
  }
  float sum = 0.0f, w[8];
  #pragma unroll
  for (int k = 0; k < 8; k++){ w[k] = expf(s[k] - mx); sum += w[k]; }
  float rs = 1.0f / sum;
  float acc = 0.0f;
  #pragma unroll
  for (int k = 0; k < 8; k++) acc += (w[k]*rs) * b2f(Va[((size_t)((b*8 + k)*8 + t))*512 + h*64 + l]);
  O[qoff] = __float2bfloat16(acc);
}

// ==================== BEV cross-attention: Q/O [2560,512] bf16, K/V [4096,512] bf16; grid (16,8,4) ====================
// K staged TRANSPOSED in LDS [e][p]; 8 queries per inner iteration.
__global__ __launch_bounds__(256) void k_vattn(const bf16* __restrict__ Q, const bf16* __restrict__ Kb,
                                               const bf16* __restrict__ Vb, bf16* __restrict__ O)
{
  __shared__ unsigned short Ks[64][256];  // [e][p]
  __shared__ float qs[8][64];
  __shared__ float wgt[8][256];
  __shared__ float part[4][8][64];
  __shared__ float red[8][4];
  int bl = blockIdx.x;          // local b (0..15)
  int h = blockIdx.y, qc = blockIdx.z;
  int tid = threadIdx.x;
  const unsigned short* Kraw = (const unsigned short*)Kb;
  #pragma unroll
  for (int i = 0; i < 16; i++){
    int idx = i*1024 + tid*4;
    int p = idx >> 6, e0 = idx & 63;
    us4 kv = *(const us4*)&Kraw[((size_t)(bl*256 + p))*512 + h*64 + e0];
    Ks[e0+0][p] = kv.x; Ks[e0+1][p] = kv.y; Ks[e0+2][p] = kv.z; Ks[e0+3][p] = kv.w;
  }
  __syncthreads();
  int g = tid >> 6, e = tid & 63;
  for (int q0 = qc*40; q0 < qc*40 + 40; q0 += 8){
    #pragma unroll
    for (int rep = 0; rep < 2; rep++){
      int q = rep*4 + (tid >> 6); int ee = tid & 63;
      qs[q][ee] = b2f(Q[((size_t)(bl*160 + q0 + q))*512 + h*64 + ee]);
    }
    __syncthreads();
    // scores: thread tid <-> key p = tid
    float s[8] = {0,0,0,0,0,0,0,0};
    #pragma unroll 4
    for (int e2 = 0; e2 < 64; e2++){
      float kv = u2f(Ks[e2][tid]);
      #pragma unroll
      for (int q = 0; q < 8; q++) s[q] += qs[q][e2]*kv;
    }
    #pragma unroll
    for (int q = 0; q < 8; q++){
      s[q] *= 0.125f;
      float mx = s[q];
      #pragma unroll
      for (int o = 32; o > 0; o >>= 1) mx = fmaxf(mx, __shfl_xor(mx, o));
      if ((tid & 63) == 0) red[q][tid >> 6] = mx;
    }
    __syncthreads();
    float ex[8];
    #pragma unroll
    for (int q = 0; q < 8; q++){
      float mx = fmaxf(fmaxf(red[q][0],red[q][1]), fmaxf(red[q][2],red[q][3]));
      ex[q] = expf(s[q] - mx);
    }
    __syncthreads();
    #pragma unroll
    for (int q = 0; q < 8; q++){
      float sm = ex[q];
      #pragma unroll
      for (int o = 32; o > 0; o >>= 1) sm += __shfl_xor(sm, o);
      if ((tid & 63) == 0) red[q][tid >> 6] = sm;
    }
    __syncthreads();
    #pragma unroll
    for (int q = 0; q < 8; q++){
      float sm = red[q][0]+red[q][1]+red[q][2]+red[q][3];
      wgt[q][tid] = ex[q] / sm;
    }
    __syncthreads();
    float acc[8] = {0,0,0,0,0,0,0,0};
    for (int j = 0; j < 64; j++){
      int p = g*64 + j;
      float v = b2f(Vb[((size_t)(bl*256 + p))*512 + h*64 + e]);
      #pragma unroll
      for (int q = 0; q < 8; q++) acc[q] += wgt[q][p]*v;
    }
    #pragma unroll
    for (int q = 0; q < 8; q++) part[g][q][e] = acc[q];
    __syncthreads();
    #pragma unroll
    for (int rep = 0; rep < 2; rep++){
      int q = rep*4 + (tid >> 6); int ee = tid & 63;
      float o = part[0][q][ee]+part[1][q][ee]+part[2][q][ee]+part[3][q][ee];
      O[((size_t)(bl*160 + q0 + q))*512 + h*64 + ee] = __float2bfloat16(o);
    }
    __syncthreads();
  }
}

// ==================== f32 rows -> bf16 rows ====================
__global__ void k_cvtrows(const float* __restrict__ src, bf16* __restrict__ dst){
  int r = blockIdx.x, t = threadIdx.x;
  dst[(size_t)r*512 + t]       = __float2bfloat16(src[(size_t)r*512 + t]);
  dst[(size_t)r*512 + t + 256] = __float2bfloat16(src[(size_t)r*512 + t + 256]);
}

extern "C" void kernel_launch(void* const* d_in, const int* in_sizes, int n_in,
                              void* d_out, int out_size, void* d_ws, size_t ws_size,
                              hipStream_t stream)
{
  (void)in_sizes; (void)n_in; (void)out_size;
  const float* ego_query    = (const float*)d_in[0];
  const float* agents_query = (const float*)d_in[1];
  const float* bev_feature  = (const float*)d_in[2];
  const float* agent_states = (const float*)d_in[3];
  const float* agent_labels = (const float*)d_in[4];
  const float* gt_traj      = (const float*)d_in[5];
  const float* codebook     = (const float*)d_in[6];
  const float* ego_ctx_w    = (const float*)d_in[7];
  const float* ego_ctx_b    = (const float*)d_in[8];
  const float* ego_ctx_g    = (const float*)d_in[9];
  const float* ego_ctx_beta = (const float*)d_in[10];
  const float* bevproj_w    = (const float*)d_in[11];
  const float* bevproj_b    = (const float*)d_in[12];
  const float* bevproj_g    = (const float*)d_in[13];
  const float* bevproj_beta = (const float*)d_in[14];
  const float* agent_w      = (const float*)d_in[15];
  const float* agent_b      = (const float*)d_in[16];
  const float* agent_g      = (const float*)d_in[17];
  const float* agent_beta   = (const float*)d_in[18];
  const float* tok_emb      = (const float*)d_in[19];
  const float* step_e       = (const float*)d_in[20];
  const float* mode_e       = (const float*)d_in[21];
  const float* role_e       = (const float*)d_in[22];
  const float* bos_e        = (const float*)d_in[23];
  const float* t_qkv_w      = (const float*)d_in[24];
  const float* t_qkv_b      = (const float*)d_in[25];
  const float* t_out_w      = (const float*)d_in[26];
  const float* t_out_b      = (const float*)d_in[27];
  const float* t_g          = (const float*)d_in[28];
  const float* t_beta       = (const float*)d_in[29];
  const float* e_qkv_w      = (const float*)d_in[30];
  const float* e_qkv_b      = (const float*)d_in[31];
  const float* e_out_w      = (const float*)d_in[32];
  const float* e_out_b      = (const float*)d_in[33];
  const float* e_g          = (const float*)d_in[34];
  const float* e_beta       = (const float*)d_in[35];
  const float* v_qkv_w      = (const float*)d_in[36];
  const float* v_qkv_b      = (const float*)d_in[37];
  const float* v_out_w      = (const float*)d_in[38];
  const float* v_out_b      = (const float*)d_in[39];
  const float* v_g          = (const float*)d_in[40];
  const float* v_beta       = (const float*)d_in[41];
  const float* ffn_w1       = (const float*)d_in[42];
  const float* ffn_b1       = (const float*)d_in[43];
  const float* ffn_w2       = (const float*)d_in[44];
  const float* ffn_b2       = (const float*)d_in[45];
  const float* ffn_g        = (const float*)d_in[46];
  const float* ffn_beta     = (const float*)d_in[47];
  const float* head_w       = (const float*)d_in[48];
  const float* head_b       = (const float*)d_in[49];

  // ---- workspace (byte offsets), total 37,885,952 B ----
  char* WB = (char*)d_ws;
  bf16*  akv   = (bf16*) (WB + 0);           // [4096,512] bf16
  float* ebase = (float*)(WB + 4194304);     // [64,512] f32
  bf16*  A_k   = (bf16*) (WB + 4325376);     // [4096,512] bf16
  bf16*  A_v   = (bf16*) (WB + 8519680);     // [4096,512] bf16
  bf16*  A_t   = (bf16*) (WB + 12713984);    // [4096,512] bf16 (bev tokens post-LN, per group)
  char*  ARENA = WB + 16908288;              // 20,971,520 B multi-purpose arena
  int*   toks  = (int*)(WB + 37879808);
  int*   idxb  = (int*)(WB + 37881856);
  int*   invb  = (int*)(WB + 37883904);

  const size_t NEEDED = 37885952;
  if (ws_size < NEEDED) return;

  float* egoq = (float*)d_out;   // [10240,512] f32 residual stream lives in d_out

  #define GEMM(AT,CT,ACT,BN,RES, Ap,Wp,Bp,Cp,Rp, R,K,N) \
    k_gemm_mfma<AT,CT,ACT,BN,RES><<<dim3(((R)+127)/128,(N)/(BN)),256,0,stream>>>(Ap,Wp,Bp,Cp,Rp,R,K,N)

  // --- ego base ---
  GEMM(float,float,0,64,0, ego_query, ego_ctx_w, ego_ctx_b, (float*)ARENA, nullptr, 64, 512, 512);
  k_ln<float,float><<<64, 256, 0, stream>>>((float*)ARENA, nullptr, ego_ctx_g, ego_ctx_beta, ebase, 1);

  // --- agents ---
  k_topk<<<64, 64, 0, stream>>>(agent_labels, agent_states, idxb, invb);
  {
    bf16*  gat = (bf16*)ARENA;                   // [512,512] bf16
    float* enc = (float*)(ARENA + 524288);       // [512,512] f32
    k_gather<<<512, 256, 0, stream>>>(agents_query, idxb, gat);
    GEMM(bf16,float,0,64,0, gat, agent_w, agent_b, enc, nullptr, 512, 512, 512);
    k_ln<float,float><<<512, 256, 0, stream>>>(enc, nullptr, agent_g, agent_beta, enc, 1);
    k_agentkv<<<4096, 256, 0, stream>>>(enc, step_e, role_e, akv);
  }

  // --- tokens + embedding ---
  k_cbscan<<<64, 64, 0, stream>>>(gt_traj, codebook, toks);
  k_embed<<<10240, 256, 0, stream>>>(toks, ebase, tok_emb, step_e, mode_e, role_e, bos_e, egoq);

  for (int i = 0; i < 2; i++){
    // ---- temporal self-attention (2 chunks x 5120 rows; residual fused; LN full in-place) ----
    {
      bf16* QKV = (bf16*)ARENA;                 // [5120,1536]
      bf16* Ot  = (bf16*)(ARENA + 15728640);    // [5120,512]
      for (int c = 0; c < 2; c++){
        float* eg = egoq + (size_t)c*5120*512;
        GEMM(float,bf16,0,128,0, eg, t_qkv_w + (size_t)i*786432, t_qkv_b + i*1536, QKV, nullptr, 5120, 512, 1536);
        k_tattn<<<5120, 64, 0, stream>>>(QKV, Ot);
        GEMM(bf16,float,0,64,1, Ot, t_out_w + (size_t)i*262144, t_out_b + i*512, eg, eg, 5120, 512, 512);
      }
      k_ln<float,float><<<10240, 256, 0, stream>>>(egoq, nullptr, t_g + i*512, t_beta + i*512, egoq, 0);
    }
    // ---- ego-to-agent cross-attention ----
    {
      const float* eqw = e_qkv_w + (size_t)i*786432;
      const float* eqb = e_qkv_b + i*1536;
      bf16* Qe = (bf16*)ARENA;                  // [5120,512]
      bf16* Oe = (bf16*)(ARENA + 5242880);      // [5120,512]
      GEMM(bf16,bf16,0,64,0, akv, eqw + 262144, eqb + 512,  A_k, nullptr, 4096, 512, 512);
      GEMM(bf16,bf16,0,64,0, akv, eqw + 524288, eqb + 1024, A_v, nullptr, 4096, 512, 512);
      for (int c = 0; c < 2; c++){
        float* eg = egoq + (size_t)c*5120*512;
        GEMM(float,bf16,0,64,0, eg, eqw, eqb, Qe, nullptr, 5120, 512, 512);
        k_eattn<<<dim3(5120, 8), 64, 0, stream>>>(Qe, A_k, A_v, invb, Oe, c*5120);
        GEMM(bf16,float,0,64,1, Oe, e_out_w + (size_t)i*262144, e_out_b + i*512, eg, eg, 5120, 512, 512);
      }
      k_ln<float,float><<<10240, 256, 0, stream>>>(egoq, nullptr, e_g + i*512, e_beta + i*512, egoq, 0);
    }
    // ---- BEV cross-attention (4 groups x 16 batches) ----
    {
      const float* vqw = v_qkv_w + (size_t)i*786432;
      const float* vqb = v_qkv_b + i*1536;
      bf16* raw = (bf16*)ARENA;                 // [4096,512]
      bf16* Qv  = (bf16*)(ARENA + 4194304);     // [2560,512]
      bf16* Ov  = (bf16*)(ARENA + 6815744);     // [2560,512]
      for (int gidx = 0; gidx < 4; gidx++){
        float* eg = egoq + (size_t)gidx*2560*512;
        k_bev_tok<<<dim3(16, 8, 16), dim3(32, 8), 0, stream>>>(bev_feature, raw, gidx*16);
        GEMM(bf16,bf16,0,64,0, raw, bevproj_w, bevproj_b, A_t, nullptr, 4096, 512, 512);
        k_ln<bf16,bf16><<<4096, 256, 0, stream>>>(A_t, nullptr, bevproj_g, bevproj_beta, A_t, 1);
        GEMM(bf16,bf16,0,64,0, A_t, vqw + 262144, vqb + 512,  A_k, nullptr, 4096, 512, 512);
        GEMM(bf16,bf16,0,64,0, A_t, vqw + 524288, vqb + 1024, A_v, nullptr, 4096, 512, 512);
        GEMM(float,bf16,0,64,0, eg, vqw, vqb, Qv, nullptr, 2560, 512, 512);
        k_vattn<<<dim3(16, 8, 4), 256, 0, stream>>>(Qv, A_k, A_v, Ov);
        GEMM(bf16,float,0,64,1, Ov, v_out_w + (size_t)i*262144, v_out_b + i*512, eg, eg, 2560, 512, 512);
      }
      k_ln<float,float><<<10240, 256, 0, stream>>>(egoq, nullptr, v_g + i*512, v_beta + i*512, egoq, 0);
    }
    // ---- FFN (2 chunks; GELU fused; residual fused; LN full) ----
    {
      bf16* hid = (bf16*)ARENA;                 // [5120,2048]
      for (int c = 0; c < 2; c++){
        float* eg = egoq + (size_t)c*5120*512;
        GEMM(float,bf16,1,128,0, eg, ffn_w1 + (size_t)i*1048576, ffn_b1 + i*2048, hid, nullptr, 5120, 512, 2048);
        GEMM(bf16,float,0,64,1, hid, ffn_w2 + (size_t)i*1048576, ffn_b2 + i*512, eg, eg, 5120, 2048, 512);
      }
      k_ln<float,float><<<10240, 256, 0, stream>>>(egoq, nullptr, ffn_g + i*512, ffn_beta + i*512, egoq, 0);
    }
  }

  // --- head: convert all rows to bf16 (reads d_out fully), then one GEMM writes d_out once ---
  {
    bf16* hin = (bf16*)ARENA;                   // [10240,512]
    k_cvtrows<<<10240, 256, 0, stream>>>(egoq, hin);
    GEMM(bf16,float,0,64,0, hin, head_w, head_b, (float*)d_out, nullptr, 10240, 512, 512);
  }
  #undef GEMM
}

// Round 8
// 2087.088 us; speedup vs baseline: 3.8106x; 1.2437x over previous
//
#include <hip/hip_runtime.h>
#include <hip/hip_bf16.h>
#include <math.h>
#include <type_traits>

typedef __hip_bfloat16 bf16;
typedef __attribute__((ext_vector_type(8))) short bf16x8;
typedef __attribute__((ext_vector_type(4))) float f32x4;
typedef __attribute__((ext_vector_type(4))) unsigned short us4;

__device__ __forceinline__ float b2f(bf16 x){ return __bfloat162float(x); }
__device__ __forceinline__ short f2s(float f){
  bf16 h = __float2bfloat16(f);
  short s; __builtin_memcpy(&s, &h, 2); return s;
}
__device__ __forceinline__ float u2f(unsigned short u){ union { unsigned int i; float f; } z; z.i = ((unsigned int)u) << 16; return z.f; }
__device__ __forceinline__ bf16x8 cvt8(float4 a, float4 b){
  return (bf16x8){f2s(a.x),f2s(a.y),f2s(a.z),f2s(a.w), f2s(b.x),f2s(b.y),f2s(b.z),f2s(b.w)};
}

// ==================== MFMA GEMM (software-pipelined): C = act( A*W^T + bias [+ R] ) ====================
// 128xBN tile (BN=128/64), BK=32, 4 waves, 16x16x32 bf16 MFMA, fp32 accum.
// Pipeline: regs(k) -> barrier -> LDS -> barrier -> issue loads(k+1) -> MFMA(k).
template<typename AT, typename CT, int ACT, int BN, int RES>
__global__ __launch_bounds__(256, BN == 64 ? 2 : 1)
void k_gemm_mfma(const AT* __restrict__ A, const float* __restrict__ W,
                 const float* __restrict__ bias, CT* C,
                 const float* Rres, int rows, int Kd, int Nc)
{
  __shared__ short As[128][40];   // 80 B row stride
  __shared__ short Bs[BN][40];
  constexpr int NI = BN / 32;
  int rb = blockIdx.x * 128, nb = blockIdx.y * BN;
  int tid = threadIdx.x;
  int l = tid & 63, w = tid >> 6;
  int wr = (w >> 1) * 64, wc = (w & 1) * (BN/2);
  int lr = l & 15, lk = l >> 4;
  f32x4 acc[4][NI];
  #pragma unroll
  for (int i = 0; i < 4; i++)
    #pragma unroll
    for (int j = 0; j < NI; j++)
      acc[i][j] = (f32x4){0.f, 0.f, 0.f, 0.f};
  int sr = tid >> 1;
  int sc = (tid & 1) * 16;
  bool doB = (BN == 128) || (tid < 128);
  bool doA = (rb + sr) < rows;

  float4 fa0={0,0,0,0},fa1={0,0,0,0},fa2={0,0,0,0},fa3={0,0,0,0};
  float4 fb0={0,0,0,0},fb1={0,0,0,0},fb2={0,0,0,0},fb3={0,0,0,0};
  bf16x8 ba0={0,0,0,0,0,0,0,0}, ba1={0,0,0,0,0,0,0,0};

  auto LOAD = [&](int k0){
    if constexpr (std::is_same<AT, float>::value){
      if (doA){
        const float4* p = (const float4*)(A + (size_t)(rb + sr)*Kd + k0 + sc);
        fa0 = p[0]; fa1 = p[1]; fa2 = p[2]; fa3 = p[3];
      }
    } else {
      if (doA){
        const bf16x8* p = (const bf16x8*)((const unsigned short*)A + (size_t)(rb + sr)*Kd + k0 + sc);
        ba0 = p[0]; ba1 = p[1];
      }
    }
    if (doB){
      const float4* p = (const float4*)(W + (size_t)(nb + sr)*Kd + k0 + sc);
      fb0 = p[0]; fb1 = p[1]; fb2 = p[2]; fb3 = p[3];
    }
  };

  LOAD(0);
  for (int k0 = 0; k0 < Kd; k0 += 32){
    __syncthreads();   // prior iteration's frag reads complete
    if constexpr (std::is_same<AT, float>::value){
      *(bf16x8*)&As[sr][sc]     = cvt8(fa0, fa1);
      *(bf16x8*)&As[sr][sc + 8] = cvt8(fa2, fa3);
    } else {
      *(bf16x8*)&As[sr][sc]     = ba0;
      *(bf16x8*)&As[sr][sc + 8] = ba1;
    }
    if (doB){
      *(bf16x8*)&Bs[sr][sc]     = cvt8(fb0, fb1);
      *(bf16x8*)&Bs[sr][sc + 8] = cvt8(fb2, fb3);
    }
    __syncthreads();
    if (k0 + 32 < Kd) LOAD(k0 + 32);   // issue next-tile loads; latency hides under MFMA
    bf16x8 af[4], bf_[NI];
    #pragma unroll
    for (int mi = 0; mi < 4; mi++) af[mi]  = *(const bf16x8*)&As[wr + mi*16 + lr][lk*8];
    #pragma unroll
    for (int ni = 0; ni < NI; ni++) bf_[ni] = *(const bf16x8*)&Bs[wc + ni*16 + lr][lk*8];
    #pragma unroll
    for (int mi = 0; mi < 4; mi++)
      #pragma unroll
      for (int ni = 0; ni < NI; ni++)
        acc[mi][ni] = __builtin_amdgcn_mfma_f32_16x16x32_bf16(af[mi], bf_[ni], acc[mi][ni], 0, 0, 0);
  }

  #pragma unroll
  for (int mi = 0; mi < 4; mi++){
    #pragma unroll
    for (int ni = 0; ni < NI; ni++){
      int col = nb + wc + ni*16 + lr;
      float bs = bias[col];
      #pragma unroll
      for (int r = 0; r < 4; r++){
        int row = rb + wr + mi*16 + lk*4 + r;
        if (row < rows){
          float v = acc[mi][ni][r] + bs;
          if (RES) v += Rres[(size_t)row*Nc + col];
          if (ACT == 1) v = 0.5f*v*(1.0f + erff(v*0.70710678118654752f));
          if constexpr (std::is_same<CT, float>::value) C[(size_t)row*Nc + col] = v;
          else C[(size_t)row*Nc + col] = __float2bfloat16(v);
        }
      }
    }
  }
}

// ==================== row LayerNorm (D=512), optional residual + relu. NO restrict (may run in place). ====================
template<typename XT, typename OT>
__global__ __launch_bounds__(256) void k_ln(const XT* X, const float* R,
                                            const float* g, const float* bt,
                                            OT* out, int relu)
{
  __shared__ float red[4];
  int row = blockIdx.x, t = threadIdx.x;
  size_t base = (size_t)row * 512;
  float x0, x1;
  if constexpr (std::is_same<XT, float>::value){ x0 = X[base + t]; x1 = X[base + t + 256]; }
  else { x0 = b2f(X[base + t]); x1 = b2f(X[base + t + 256]); }
  if (R){ x0 += R[base + t]; x1 += R[base + t + 256]; }
  float v = x0 + x1;
  #pragma unroll
  for (int o = 32; o > 0; o >>= 1) v += __shfl_xor(v, o);
  if ((t & 63) == 0) red[t >> 6] = v;
  __syncthreads();
  float mean = (red[0]+red[1]+red[2]+red[3]) * (1.0f/512.0f);
  float d0 = x0 - mean, d1 = x1 - mean;
  v = d0*d0 + d1*d1;
  #pragma unroll
  for (int o = 32; o > 0; o >>= 1) v += __shfl_xor(v, o);
  __syncthreads();
  if ((t & 63) == 0) red[t >> 6] = v;
  __syncthreads();
  float var = (red[0]+red[1]+red[2]+red[3]) * (1.0f/512.0f);
  float is = 1.0f / sqrtf(var + 1e-5f);
  float y0 = d0*is*g[t] + bt[t];
  float y1 = d1*is*g[t+256] + bt[t+256];
  if (relu){ y0 = fmaxf(y0, 0.0f); y1 = fmaxf(y1, 0.0f); }
  if constexpr (std::is_same<OT, float>::value){ out[base + t] = y0; out[base + t + 256] = y1; }
  else { out[base + t] = __float2bfloat16(y0); out[base + t + 256] = __float2bfloat16(y1); }
}

// ==================== bev transpose [64, 512, 256] f32 -> [16384, 512] bf16 ====================
__global__ void k_bev_tok(const float* __restrict__ bev, bf16* __restrict__ out){
  __shared__ float tile[32][33];
  int b = blockIdx.z;
  int d0 = blockIdx.x * 32;
  int p0 = blockIdx.y * 32;
  int tx = threadIdx.x, ty = threadIdx.y;
  #pragma unroll
  for (int i = 0; i < 4; i++){
    int d = d0 + ty + i*8;
    tile[ty + i*8][tx] = bev[((size_t)b*512 + d)*256 + p0 + tx];
  }
  __syncthreads();
  #pragma unroll
  for (int i = 0; i < 4; i++){
    int p = p0 + ty + i*8;
    out[((size_t)b*256 + p)*512 + d0 + tx] = __float2bfloat16(tile[tx][ty + i*8]);
  }
}

// ==================== top-K agents + invalid mask ====================
__global__ void k_topk(const float* __restrict__ labels, const float* __restrict__ states,
                       int* __restrict__ idxo, int* __restrict__ invo)
{
  __shared__ float dist[32];
  __shared__ int valid[32];
  int b = blockIdx.x, t = threadIdx.x;
  if (t < 32){
    float lab = labels[b*32 + t];
    float sg = 1.0f / (1.0f + expf(-lab));
    int va = sg > 0.05f;
    float x = states[((size_t)b*32 + t)*8 + 0];
    float y = states[((size_t)b*32 + t)*8 + 1];
    float d = sqrtf(__fadd_rn(__fmul_rn(x,x), __fmul_rn(y,y)));
    dist[t] = va ? d : INFINITY;
    valid[t] = va;
  }
  __syncthreads();
  if (t == 0){
    unsigned used = 0;
    int inv8[8]; int allinv = 1;
    for (int kk = 0; kk < 8; kk++){
      float best = INFINITY; int bi = -1;
      for (int i = 0; i < 32; i++){
        if (used & (1u << i)) continue;
        if (bi < 0 || dist[i] < best){ best = dist[i]; bi = i; }
      }
      used |= 1u << bi;
      idxo[b*8 + kk] = bi;
      inv8[kk] = !valid[bi];
      allinv &= inv8[kk];
    }
    for (int kk = 0; kk < 8; kk++) invo[b*8 + kk] = allinv ? 0 : inv8[kk];
  }
}

// ==================== gather agents f32 -> bf16 [512,512] ====================
__global__ void k_gather(const float* __restrict__ aq, const int* __restrict__ idx, bf16* __restrict__ out)
{
  int rk = blockIdx.x; int b = rk >> 3;
  int src = idx[rk] & 31;
  int t = threadIdx.x;
  size_t sbase = ((size_t)(b*32 + src))*512;
  out[(size_t)rk*512 + t]       = __float2bfloat16(aq[sbase + t]);
  out[(size_t)rk*512 + t + 256] = __float2bfloat16(aq[sbase + t + 256]);
}

// ==================== agent_kv f32 enc -> bf16 [4096,512] ====================
__global__ void k_agentkv(const float* __restrict__ enc, const float* __restrict__ step_e,
                          const float* __restrict__ role_e, bf16* __restrict__ out)
{
  int row = blockIdx.x;
  int t8 = row & 7; int bk = row >> 3;
  int tx = threadIdx.x;
  #pragma unroll
  for (int j = 0; j < 2; j++){
    int d = tx + j*256;
    out[(size_t)row*512 + d] = __float2bfloat16((enc[(size_t)bk*512 + d] + step_e[t8*512 + d]) + role_e[512 + d]);
  }
}

// ==================== sequential codebook NN scan -> tokens [B,T] ====================
__global__ __launch_bounds__(64) void k_cbscan(const float* __restrict__ gt, const float* __restrict__ cb,
                                               int* __restrict__ toks)
{
  __shared__ float cbx[512], cby[512];
  int b = blockIdx.x;
  int l = threadIdx.x;
  #pragma unroll
  for (int i = 0; i < 8; i++){
    int v = l + i*64;
    cbx[v] = cb[v*2 + 0];
    cby[v] = cb[v*2 + 1];
  }
  __syncthreads();
  float ax = 0.0f, ay = 0.0f;
  for (int t = 0; t < 8; t++){
    float px = gt[(b*8 + t)*3 + 0];
    float py = gt[(b*8 + t)*3 + 1];
    float bestv = INFINITY; int besti = 0;
    #pragma unroll
    for (int i = 0; i < 8; i++){
      int v = l*8 + i;
      float dx = __fsub_rn(__fadd_rn(ax, cbx[v]), px);
      float dy = __fsub_rn(__fadd_rn(ay, cby[v]), py);
      float d = __fadd_rn(__fmul_rn(dx,dx), __fmul_rn(dy,dy));
      if (d < bestv || (d == bestv && v < besti)){ bestv = d; besti = v; }
    }
    #pragma unroll
    for (int o = 32; o > 0; o >>= 1){
      float ov = __shfl_xor(bestv, o);
      int oi = __shfl_xor(besti, o);
      if (ov < bestv || (ov == bestv && oi < besti)){ bestv = ov; besti = oi; }
    }
    ax = __fadd_rn(ax, cbx[besti]);
    ay = __fadd_rn(ay, cby[besti]);
    if (l == 0) toks[b*8 + t] = besti;
  }
}

// ==================== teacher-forced embedding -> egoq f32 ====================
__global__ void k_embed(const int* __restrict__ toks, const float* __restrict__ ebase,
                        const float* __restrict__ tok_emb, const float* __restrict__ step_e,
                        const float* __restrict__ mode_e, const float* __restrict__ role_e,
                        const float* __restrict__ bos_e, float* __restrict__ out)
{
  int row = blockIdx.x;
  int t = row & 7; int bm = row >> 3; int m = bm % 20; int b = bm / 20;
  int tok = (t == 0) ? 0 : (toks[b*8 + t - 1] & 511);
  int tx = threadIdx.x;
  #pragma unroll
  for (int j = 0; j < 2; j++){
    int d = tx + j*256;
    float base = (t == 0) ? (bos_e[d] + ebase[(size_t)b*512 + d])
                          : tok_emb[(size_t)tok*512 + d];
    out[(size_t)row*512 + d] = ((base + step_e[t*512 + d]) + role_e[d]) + mode_e[m*512 + d];
  }
}

// ==================== temporal causal attention (QKV bf16 [rows,1536] -> O bf16) ====================
__global__ __launch_bounds__(64) void k_tattn(const bf16* __restrict__ QKV, bf16* __restrict__ O)
{
  __shared__ float q[8][65], k[8][65], v[8][65], w[8][9];
  int h = blockIdx.x & 7; int bm = blockIdx.x >> 3;
  int l = threadIdx.x;
  for (int t = 0; t < 8; t++){
    size_t base = ((size_t)(bm*8 + t))*1536 + h*64 + l;
    q[t][l] = b2f(QKV[base]);
    k[t][l] = b2f(QKV[base + 512]);
    v[t][l] = b2f(QKV[base + 1024]);
  }
  __syncthreads();
  int tq = l >> 3, tk = l & 7;
  float s = -INFINITY;
  if (tk <= tq){
    float acc = 0.0f;
    #pragma unroll
    for (int e = 0; e < 64; e++) acc += q[tq][e]*k[tk][e];
    s = acc * 0.125f;
  }
  float mx = s;
  #pragma unroll
  for (int o = 1; o < 8; o <<= 1) mx = fmaxf(mx, __shfl_xor(mx, o));
  float ex = (tk <= tq) ? expf(s - mx) : 0.0f;
  float sm = ex;
  #pragma unroll
  for (int o = 1; o < 8; o <<= 1) sm += __shfl_xor(sm, o);
  w[tq][tk] = ex / sm;
  __syncthreads();
  #pragma unroll
  for (int t2 = 0; t2 < 8; t2++){
    float acc = 0.0f;
    #pragma unroll
    for (int tk2 = 0; tk2 < 8; tk2++) acc += w[t2][tk2]*v[tk2][l];
    O[((size_t)(bm*8 + t2))*512 + h*64 + l] = __float2bfloat16(acc);
  }
}

// ==================== ego-to-agent cross-attention; KV interleaved [4096,1024] (K|V) ====================
__global__ __launch_bounds__(64) void k_eattn(const bf16* __restrict__ Q, const bf16* __restrict__ KV,
                                              const int* __restrict__ inv,
                                              bf16* __restrict__ O, int row0)
{
  int blk = blockIdx.x;
  int h = blockIdx.y;
  int grow = row0 + blk;
  int t = grow & 7;
  int b = grow / 160;
  int l = threadIdx.x;
  size_t qoff = (size_t)blk*512 + h*64 + l;
  float q = b2f(Q[qoff]);
  float s[8];
  #pragma unroll
  for (int k = 0; k < 8; k++){
    float p = q * b2f(KV[((size_t)((b*8 + k)*8 + t))*1024 + h*64 + l]);
    #pragma unroll
    for (int o = 32; o > 0; o >>= 1) p += __shfl_xor(p, o);
    s[k] = p * 0.125f;
  }
  float mx = -INFINITY;
  #pragma unroll
  for (int k = 0; k < 8; k++){
    if (inv[b*8 + k]) s[k] = -INFINITY;
    mx = fmaxf(mx, s[k]);
  }
  float sum = 0.0f, w[8];
  #pragma unroll
  for (int k = 0; k < 8; k++){ w[k] = expf(s[k] - mx); sum += w[k]; }
  float rs = 1.0f / sum;
  float acc = 0.0f;
  #pragma unroll
  for (int k = 0; k < 8; k++)
    acc += (w[k]*rs) * b2f(KV[((size_t)((b*8 + k)*8 + t))*1024 + 512 + h*64 + l]);
  O[qoff] = __float2bfloat16(acc);
}

// ==================== BEV cross-attention; KV interleaved [4096,1024]; grid (16,8,4) ====================
__global__ __launch_bounds__(256) void k_vattn(const bf16* __restrict__ Q, const bf16* __restrict__ KV,
                                               bf16* __restrict__ O)
{
  __shared__ unsigned short Ks[64][256];  // [e][p]
  __shared__ float qs[8][64];
  __shared__ float wgt[8][256];
  __shared__ float part[4][8][64];
  __shared__ float red[8][4];
  int bl = blockIdx.x;          // local b (0..15)
  int h = blockIdx.y, qc = blockIdx.z;
  int tid = threadIdx.x;
  const unsigned short* Kraw = (const unsigned short*)KV;
  #pragma unroll
  for (int i = 0; i < 16; i++){
    int idx = i*1024 + tid*4;
    int p = idx >> 6, e0 = idx & 63;
    us4 kv = *(const us4*)&Kraw[((size_t)(bl*256 + p))*1024 + h*64 + e0];
    Ks[e0+0][p] = kv.x; Ks[e0+1][p] = kv.y; Ks[e0+2][p] = kv.z; Ks[e0+3][p] = kv.w;
  }
  __syncthreads();
  int g = tid >> 6, e = tid & 63;
  for (int q0 = qc*40; q0 < qc*40 + 40; q0 += 8){
    #pragma unroll
    for (int rep = 0; rep < 2; rep++){
      int q = rep*4 + (tid >> 6); int ee = tid & 63;
      qs[q][ee] = b2f(Q[((size_t)(bl*160 + q0 + q))*512 + h*64 + ee]);
    }
    __syncthreads();
    float s[8] = {0,0,0,0,0,0,0,0};
    #pragma unroll 4
    for (int e2 = 0; e2 < 64; e2++){
      float kv = u2f(Ks[e2][tid]);
      #pragma unroll
      for (int q = 0; q < 8; q++) s[q] += qs[q][e2]*kv;
    }
    #pragma unroll
    for (int q = 0; q < 8; q++){
      s[q] *= 0.125f;
      float mx = s[q];
      #pragma unroll
      for (int o = 32; o > 0; o >>= 1) mx = fmaxf(mx, __shfl_xor(mx, o));
      if ((tid & 63) == 0) red[q][tid >> 6] = mx;
    }
    __syncthreads();
    float ex[8];
    #pragma unroll
    for (int q = 0; q < 8; q++){
      float mx = fmaxf(fmaxf(red[q][0],red[q][1]), fmaxf(red[q][2],red[q][3]));
      ex[q] = expf(s[q] - mx);
    }
    __syncthreads();
    #pragma unroll
    for (int q = 0; q < 8; q++){
      float sm = ex[q];
      #pragma unroll
      for (int o = 32; o > 0; o >>= 1) sm += __shfl_xor(sm, o);
      if ((tid & 63) == 0) red[q][tid >> 6] = sm;
    }
    __syncthreads();
    #pragma unroll
    for (int q = 0; q < 8; q++){
      float sm = red[q][0]+red[q][1]+red[q][2]+red[q][3];
      wgt[q][tid] = ex[q] / sm;
    }
    __syncthreads();
    float acc[8] = {0,0,0,0,0,0,0,0};
    for (int j = 0; j < 64; j++){
      int p = g*64 + j;
      float v = b2f(KV[((size_t)(bl*256 + p))*1024 + 512 + h*64 + e]);
      #pragma unroll
      for (int q = 0; q < 8; q++) acc[q] += wgt[q][p]*v;
    }
    #pragma unroll
    for (int q = 0; q < 8; q++) part[g][q][e] = acc[q];
    __syncthreads();
    #pragma unroll
    for (int rep = 0; rep < 2; rep++){
      int q = rep*4 + (tid >> 6); int ee = tid & 63;
      float o = part[0][q][ee]+part[1][q][ee]+part[2][q][ee]+part[3][q][ee];
      O[((size_t)(bl*160 + q0 + q))*512 + h*64 + ee] = __float2bfloat16(o);
    }
    __syncthreads();
  }
}

extern "C" void kernel_launch(void* const* d_in, const int* in_sizes, int n_in,
                              void* d_out, int out_size, void* d_ws, size_t ws_size,
                              hipStream_t stream)
{
  (void)in_sizes; (void)n_in; (void)out_size;
  const float* ego_query    = (const float*)d_in[0];
  const float* agents_query = (const float*)d_in[1];
  const float* bev_feature  = (const float*)d_in[2];
  const float* agent_states = (const float*)d_in[3];
  const float* agent_labels = (const float*)d_in[4];
  const float* gt_traj      = (const float*)d_in[5];
  const float* codebook     = (const float*)d_in[6];
  const float* ego_ctx_w    = (const float*)d_in[7];
  const float* ego_ctx_b    = (const float*)d_in[8];
  const float* ego_ctx_g    = (const float*)d_in[9];
  const float* ego_ctx_beta = (const float*)d_in[10];
  const float* bevproj_w    = (const float*)d_in[11];
  const float* bevproj_b    = (const float*)d_in[12];
  const float* bevproj_g    = (const float*)d_in[13];
  const float* bevproj_beta = (const float*)d_in[14];
  const float* agent_w      = (const float*)d_in[15];
  const float* agent_b      = (const float*)d_in[16];
  const float* agent_g      = (const float*)d_in[17];
  const float* agent_beta   = (const float*)d_in[18];
  const float* tok_emb      = (const float*)d_in[19];
  const float* step_e       = (const float*)d_in[20];
  const float* mode_e       = (const float*)d_in[21];
  const float* role_e       = (const float*)d_in[22];
  const float* bos_e        = (const float*)d_in[23];
  const float* t_qkv_w      = (const float*)d_in[24];
  const float* t_qkv_b      = (const float*)d_in[25];
  const float* t_out_w      = (const float*)d_in[26];
  const float* t_out_b      = (const float*)d_in[27];
  const float* t_g          = (const float*)d_in[28];
  const float* t_beta       = (const float*)d_in[29];
  const float* e_qkv_w      = (const float*)d_in[30];
  const float* e_qkv_b      = (const float*)d_in[31];
  const float* e_out_w      = (const float*)d_in[32];
  const float* e_out_b      = (const float*)d_in[33];
  const float* e_g          = (const float*)d_in[34];
  const float* e_beta       = (const float*)d_in[35];
  const float* v_qkv_w      = (const float*)d_in[36];
  const float* v_qkv_b      = (const float*)d_in[37];
  const float* v_out_w      = (const float*)d_in[38];
  const float* v_out_b      = (const float*)d_in[39];
  const float* v_g          = (const float*)d_in[40];
  const float* v_beta       = (const float*)d_in[41];
  const float* ffn_w1       = (const float*)d_in[42];
  const float* ffn_b1       = (const float*)d_in[43];
  const float* ffn_w2       = (const float*)d_in[44];
  const float* ffn_b2       = (const float*)d_in[45];
  const float* ffn_g        = (const float*)d_in[46];
  const float* ffn_beta     = (const float*)d_in[47];
  const float* head_w       = (const float*)d_in[48];
  const float* head_b       = (const float*)d_in[49];

  // ---- workspace layout (byte offsets), total 46,274,560 B ----
  char* WB = (char*)d_ws;
  bf16*  bevtok = (bf16*)(WB + 0);          // [16384,512] bf16 (post-LN bev tokens, both layers)
  bf16*  akv    = (bf16*)(WB + 16777216);   // [4096,512] bf16
  float* ebase  = (float*)(WB + 20971520);  // [64,512] f32
  char*  ARENA  = WB + 21102592;            // 16,777,216 B
  bf16*  KVb    = (bf16*)(WB + 37879808);   // [4096,1024] bf16 (K|V interleaved) — FFN hid spans here too
  int*   toks   = (int*)(WB + 46268416);
  int*   idxb   = (int*)(WB + 46270464);
  int*   invb   = (int*)(WB + 46272512);

  const size_t NEEDED = 46274560;
  if (ws_size < NEEDED) return;

  float* egoq = (float*)d_out;   // [10240,512] f32 residual stream lives in d_out

  #define GEMM(AT,CT,ACT,BN,RES, Ap,Wp,Bp,Cp,Rp, R,K,N) \
    k_gemm_mfma<AT,CT,ACT,BN,RES><<<dim3(((R)+127)/128,(N)/(BN)),256,0,stream>>>(Ap,Wp,Bp,Cp,Rp,R,K,N)

  // --- BEV tokens ONCE (transpose -> proj -> LN+relu), reused by both layers ---
  {
    bf16* raw = (bf16*)ARENA;   // [16384,512]
    k_bev_tok<<<dim3(16, 8, 64), dim3(32, 8), 0, stream>>>(bev_feature, raw);
    GEMM(bf16,bf16,0,64,0, raw, bevproj_w, bevproj_b, bevtok, nullptr, 16384, 512, 512);
    k_ln<bf16,bf16><<<16384, 256, 0, stream>>>(bevtok, nullptr, bevproj_g, bevproj_beta, bevtok, 1);
  }

  // --- ego base ---
  GEMM(float,float,0,64,0, ego_query, ego_ctx_w, ego_ctx_b, (float*)ARENA, nullptr, 64, 512, 512);
  k_ln<float,float><<<64, 256, 0, stream>>>((float*)ARENA, nullptr, ego_ctx_g, ego_ctx_beta, ebase, 1);

  // --- agents ---
  k_topk<<<64, 64, 0, stream>>>(agent_labels, agent_states, idxb, invb);
  {
    bf16*  gat = (bf16*)ARENA;                   // [512,512] bf16
    float* enc = (float*)(ARENA + 524288);       // [512,512] f32
    k_gather<<<512, 256, 0, stream>>>(agents_query, idxb, gat);
    GEMM(bf16,float,0,64,0, gat, agent_w, agent_b, enc, nullptr, 512, 512, 512);
    k_ln<float,float><<<512, 256, 0, stream>>>(enc, nullptr, agent_g, agent_beta, enc, 1);
    k_agentkv<<<4096, 256, 0, stream>>>(enc, step_e, role_e, akv);
  }

  // --- tokens + embedding ---
  k_cbscan<<<64, 64, 0, stream>>>(gt_traj, codebook, toks);
  k_embed<<<10240, 256, 0, stream>>>(toks, ebase, tok_emb, step_e, mode_e, role_e, bos_e, egoq);

  for (int i = 0; i < 2; i++){
    // ---- temporal self-attention (2 chunks x 5120 rows; residual fused; full in-place LN) ----
    {
      bf16* QKV = (bf16*)ARENA;   // [5120,1536]
      bf16* Ot  = KVb;            // [5120,512] (KV region free during this phase)
      for (int c = 0; c < 2; c++){
        float* eg = egoq + (size_t)c*5120*512;
        GEMM(float,bf16,0,128,0, eg, t_qkv_w + (size_t)i*786432, t_qkv_b + i*1536, QKV, nullptr, 5120, 512, 1536);
        k_tattn<<<5120, 64, 0, stream>>>(QKV, Ot);
        GEMM(bf16,float,0,64,1, Ot, t_out_w + (size_t)i*262144, t_out_b + i*512, eg, eg, 5120, 512, 512);
      }
      k_ln<float,float><<<10240, 256, 0, stream>>>(egoq, nullptr, t_g + i*512, t_beta + i*512, egoq, 0);
    }
    // ---- ego-to-agent cross-attention (single KV GEMM, N=1024: K|V weights contiguous) ----
    {
      const float* eqw = e_qkv_w + (size_t)i*786432;
      const float* eqb = e_qkv_b + i*1536;
      bf16* Qe = (bf16*)ARENA;                  // [5120,512]
      bf16* Oe = (bf16*)(ARENA + 5242880);      // [5120,512]
      GEMM(bf16,bf16,0,64,0, akv, eqw + 262144, eqb + 512, KVb, nullptr, 4096, 512, 1024);
      for (int c = 0; c < 2; c++){
        float* eg = egoq + (size_t)c*5120*512;
        GEMM(float,bf16,0,64,0, eg, eqw, eqb, Qe, nullptr, 5120, 512, 512);
        k_eattn<<<dim3(5120, 8), 64, 0, stream>>>(Qe, KVb, invb, Oe, c*5120);
        GEMM(bf16,float,0,64,1, Oe, e_out_w + (size_t)i*262144, e_out_b + i*512, eg, eg, 5120, 512, 512);
      }
      k_ln<float,float><<<10240, 256, 0, stream>>>(egoq, nullptr, e_g + i*512, e_beta + i*512, egoq, 0);
    }
    // ---- BEV cross-attention (4 groups x 16 batches; single KV GEMM per group) ----
    {
      const float* vqw = v_qkv_w + (size_t)i*786432;
      const float* vqb = v_qkv_b + i*1536;
      bf16* Qv = (bf16*)ARENA;                  // [2560,512]
      bf16* Ov = (bf16*)(ARENA + 2621440);      // [2560,512]
      for (int gidx = 0; gidx < 4; gidx++){
        float* eg = egoq + (size_t)gidx*2560*512;
        GEMM(bf16,bf16,0,64,0, bevtok + (size_t)gidx*4096*512, vqw + 262144, vqb + 512, KVb, nullptr, 4096, 512, 1024);
        GEMM(float,bf16,0,64,0, eg, vqw, vqb, Qv, nullptr, 2560, 512, 512);
        k_vattn<<<dim3(16, 8, 4), 256, 0, stream>>>(Qv, KVb, Ov);
        GEMM(bf16,float,0,64,1, Ov, v_out_w + (size_t)i*262144, v_out_b + i*512, eg, eg, 2560, 512, 512);
      }
      k_ln<float,float><<<10240, 256, 0, stream>>>(egoq, nullptr, v_g + i*512, v_beta + i*512, egoq, 0);
    }
    // ---- FFN (2 chunks; GELU + residual fused; hid spans ARENA+KV region) ----
    {
      bf16* hid = (bf16*)ARENA;   // [5120,2048] = 20.97 MB (phase-local)
      for (int c = 0; c < 2; c++){
        float* eg = egoq + (size_t)c*5120*512;
        GEMM(float,bf16,1,128,0, eg, ffn_w1 + (size_t)i*1048576, ffn_b1 + i*2048, hid, nullptr, 5120, 512, 2048);
        GEMM(bf16,float,0,64,1, hid, ffn_w2 + (size_t)i*1048576, ffn_b2 + i*512, eg, eg, 5120, 2048, 512);
      }
      if (i == 0){
        k_ln<float,float><<<10240, 256, 0, stream>>>(egoq, nullptr, ffn_g, ffn_beta, egoq, 0);
      } else {
        // final LN emits bf16 head input directly
        k_ln<float,bf16><<<10240, 256, 0, stream>>>(egoq, nullptr, ffn_g + 512, ffn_beta + 512, (bf16*)ARENA, 0);
      }
    }
  }

  // --- head: one GEMM from bf16 head input back into d_out ---
  GEMM(bf16,float,0,64,0, (bf16*)ARENA, head_w, head_b, (float*)d_out, nullptr, 10240, 512, 512);
  #undef GEMM
}